// Round 1
// baseline (203.060 us; speedup 1.0000x reference)
//
#include <hip/hip_runtime.h>
#include <hip/hip_bf16.h>
#include <cstdint>

#define NCLS 3

typedef __attribute__((ext_vector_type(8))) __bf16 bf8;
typedef __attribute__((ext_vector_type(4))) float f32x4;

// order-preserving float<->uint maps (for atomicMin/Max on sim values)
__device__ __forceinline__ unsigned mapf(float x){
  unsigned u = __float_as_uint(x);
  return (u & 0x80000000u) ? ~u : (u | 0x80000000u);
}
__device__ __forceinline__ float unmapf(unsigned u){
  return __uint_as_float((u & 0x80000000u) ? (u & 0x7FFFFFFFu) : ~u);
}

__device__ float digammaf_(float x){
  float r = 0.f;
  while (x < 6.f){ r -= 1.f/x; x += 1.f; }
  float inv = 1.f/x, inv2 = inv*inv;
  r += logf(x) - 0.5f*inv
     - inv2*(0.08333333333f - inv2*(0.008333333333f - inv2*0.003968253968f));
  return r;
}

// ---------------- init: zero accumulators, init row min/max ----------------
__global__ void k_init(float* acc, unsigned* cnts, unsigned* rowMinU, unsigned* rowMaxU, int B){
  int i = blockIdx.x*blockDim.x + threadIdx.x;
  if (i < B){ rowMinU[i] = 0xFFFFFFFFu; rowMaxU[i] = 0u; }
  if (i < 16) acc[i] = 0.f;
  if (i < NCLS) cnts[i] = 0u;
}

// ---------------- normalize features -> bf16 ----------------
__global__ __launch_bounds__(256) void k_norm(const float* __restrict__ feat,
                                              __bf16* __restrict__ fb, int B, int D){
  int wave = threadIdx.x >> 6, lane = threadIdx.x & 63;
  int row = blockIdx.x*4 + wave;
  if (row >= B) return;
  const float* src = feat + (size_t)row*D;
  float ss = 0.f;
  for (int c = lane*4; c < D; c += 64*4){
    float4 v = *(const float4*)(src + c);
    ss += v.x*v.x + v.y*v.y + v.z*v.z + v.w*v.w;
  }
  #pragma unroll
  for (int off=32; off; off>>=1) ss += __shfl_xor(ss, off);
  float inv = 1.f / fmaxf(sqrtf(ss), 1e-12f);
  __bf16* dst = fb + (size_t)row*D;
  for (int c = lane*8; c < D; c += 64*8){
    float4 v0 = *(const float4*)(src + c);
    float4 v1 = *(const float4*)(src + c + 4);
    bf8 o;
    o[0]=(__bf16)(v0.x*inv); o[1]=(__bf16)(v0.y*inv);
    o[2]=(__bf16)(v0.z*inv); o[3]=(__bf16)(v0.w*inv);
    o[4]=(__bf16)(v1.x*inv); o[5]=(__bf16)(v1.y*inv);
    o[6]=(__bf16)(v1.z*inv); o[7]=(__bf16)(v1.w*inv);
    *(bf8*)(dst + c) = o;
  }
}

// ---------------- per-sample losses (focal, wCE, boundary, evidential) -----
__global__ __launch_bounds__(256) void k_sample(const float* __restrict__ logits,
    const int* __restrict__ targets, const float* __restrict__ alpha,
    const float* __restrict__ fa, const float* __restrict__ cw,
    int B, float* acc, unsigned* cnts){
  int i = blockIdx.x*blockDim.x + threadIdx.x;
  float focal_i=0, ce_n=0, ce_d=0, bnd=0, lik=0, kl=0;
  int t = 0; bool active = i < B;
  if (active){
    float l0=logits[3*i], l1=logits[3*i+1], l2=logits[3*i+2];
    t = targets[i];
    float m = fmaxf(l0, fmaxf(l1,l2));
    float e0=expf(l0-m), e1=expf(l1-m), e2=expf(l2-m);
    float se = e0+e1+e2;
    float lse = m + logf(se);
    float lp0=l0-lse, lp1=l1-lse, lp2=l2-lse;
    float lpt = (t==0)?lp0:((t==1)?lp1:lp2);
    float nll = -lpt;
    float ce_ls = 0.9f*nll + 0.1f*(-(lp0+lp1+lp2)*(1.f/3.f));
    float pt = expf(-ce_ls);
    float om = 1.f - pt;
    focal_i = fa[t]*om*om*ce_ls;
    float w = cw[t];
    ce_n = w*nll; ce_d = w;
    float p0=e0/se, p1=e1/se, p2=e2/se;
    if (t==0)      bnd = p1 + 0.6f*p2;
    else if (t==2) bnd = p1 + 0.4f*p0;
    else           bnd = 4.5f*(1.f - p1 + 0.3f*(p0+p2));
    float a0=alpha[3*i], a1=alpha[3*i+1], a2=alpha[3*i+2];
    float S = a0+a1+a2 + 1e-8f;
    float at_ = (t==0)?a0:((t==1)?a1:a2);
    lik = digammaf_(S) - digammaf_(at_ + 1e-8f);
    float b0 = (t==0)?1.f:a0, b1 = (t==1)?1.f:a1, b2 = (t==2)?1.f:a2;
    float ats = b0+b1+b2 + 1e-8f;
    float psa = digammaf_(ats + 1e-8f);
    kl = lgammaf(ats)
       - (lgammaf(b0+1e-8f)+lgammaf(b1+1e-8f)+lgammaf(b2+1e-8f))
       + (b0-1.f)*(digammaf_(b0+1e-8f)-psa)
       + (b1-1.f)*(digammaf_(b1+1e-8f)-psa)
       + (b2-1.f)*(digammaf_(b2+1e-8f)-psa);
  }
  unsigned long long m0 = __ballot(active && t==0);
  unsigned long long m1 = __ballot(active && t==1);
  unsigned long long m2 = __ballot(active && t==2);
  #pragma unroll
  for (int off=32; off; off>>=1){
    focal_i += __shfl_xor(focal_i, off);
    ce_n    += __shfl_xor(ce_n, off);
    ce_d    += __shfl_xor(ce_d, off);
    bnd     += __shfl_xor(bnd, off);
    lik     += __shfl_xor(lik, off);
    kl      += __shfl_xor(kl, off);
  }
  if ((threadIdx.x & 63) == 0){
    atomicAdd(&acc[4], focal_i); atomicAdd(&acc[5], ce_n); atomicAdd(&acc[6], ce_d);
    atomicAdd(&acc[7], bnd);     atomicAdd(&acc[8], lik);  atomicAdd(&acc[9], kl);
    atomicAdd(&cnts[0], (unsigned)__popcll(m0));
    atomicAdd(&cnts[1], (unsigned)__popcll(m1));
    atomicAdd(&cnts[2], (unsigned)__popcll(m2));
  }
}

// ---------------- pair kernel: fused sim reductions via MFMA ----------------
// 128x128 block tile, 4 waves 2x2, each wave 64x64 = 4x4 mfma_f32_16x16x32_bf16
__global__ __launch_bounds__(256) void k_pairs(const __bf16* __restrict__ fb,
    const int* __restrict__ targets, int B, int D,
    float* acc, unsigned* rowMinU, unsigned* rowMaxU){
  int nt = B / 128;
  int bx = blockIdx.x % nt, by = blockIdx.x / nt;
  int lane = threadIdx.x & 63, wave = threadIdx.x >> 6;
  int wr = wave >> 1, wc = wave & 1;
  int rowBase = by*128 + wr*64;
  int colBase = bx*128 + wc*64;
  int quad = lane >> 4, l16 = lane & 15;

  f32x4 C[4][4] = {};
  const __bf16* pa[4]; const __bf16* pb[4];
  #pragma unroll
  for (int mi=0;mi<4;mi++) pa[mi] = fb + (size_t)(rowBase + mi*16 + l16)*D + quad*8;
  #pragma unroll
  for (int ni=0;ni<4;ni++) pb[ni] = fb + (size_t)(colBase + ni*16 + l16)*D + quad*8;

  for (int k0=0; k0<D; k0+=32){
    bf8 aF[4], bF[4];
    #pragma unroll
    for (int mi=0;mi<4;mi++){ aF[mi] = *(const bf8*)pa[mi]; pa[mi] += 32; }
    #pragma unroll
    for (int ni=0;ni<4;ni++){ bF[ni] = *(const bf8*)pb[ni]; pb[ni] += 32; }
    #pragma unroll
    for (int mi=0;mi<4;mi++)
      #pragma unroll
      for (int ni=0;ni<4;ni++)
        C[mi][ni] = __builtin_amdgcn_mfma_f32_16x16x32_bf16(aF[mi], bF[ni], C[mi][ni], 0,0,0);
  }

  // ---- fused epilogue: masked sums + per-row min(sim_same)/max(sim_diff) ----
  int tcol[4];
  #pragma unroll
  for (int ni=0;ni<4;ni++) tcol[ni] = targets[colBase + ni*16 + l16];

  float pos=0.f, neg=0.f, semi=0.f, diag=0.f;
  #pragma unroll
  for (int mi=0;mi<4;mi++){
    #pragma unroll
    for (int r=0;r<4;r++){
      int row = rowBase + mi*16 + quad*4 + r;
      int tr = targets[row];
      float vmin = 2.f, vmax = -2.f;
      #pragma unroll
      for (int ni=0;ni<4;ni++){
        int col = colBase + ni*16 + l16;
        float s = C[mi][ni][r];
        float omv = 1.f - s;
        if (tr == tcol[ni]){
          float q = omv*omv;
          pos += q;
          if (tr == 1) semi += q;
          if (row == col) diag += q;
          else vmin = fminf(vmin, s);
        } else {
          float c0 = fmaxf(s - 0.2f, 0.f);
          neg += c0*c0;
          vmax = fmaxf(vmax, s);
        }
      }
      // reduce min/max across the 16 lanes of this quad (they share `row`)
      #pragma unroll
      for (int off=1; off<16; off<<=1){
        vmin = fminf(vmin, __shfl_xor(vmin, off));
        vmax = fmaxf(vmax, __shfl_xor(vmax, off));
      }
      if (l16 == 0){
        atomicMin(&rowMinU[row], mapf(vmin));
        atomicMax(&rowMaxU[row], mapf(vmax));
      }
    }
  }
  #pragma unroll
  for (int off=32; off; off>>=1){
    pos  += __shfl_xor(pos, off);
    neg  += __shfl_xor(neg, off);
    semi += __shfl_xor(semi, off);
    diag += __shfl_xor(diag, off);
  }
  __shared__ float sb[4][4];
  if (lane == 0){ sb[wave][0]=pos; sb[wave][1]=neg; sb[wave][2]=semi; sb[wave][3]=diag; }
  __syncthreads();
  if (threadIdx.x == 0){
    float p=0,n=0,s2=0,d=0;
    for (int w2=0;w2<4;w2++){ p+=sb[w2][0]; n+=sb[w2][1]; s2+=sb[w2][2]; d+=sb[w2][3]; }
    atomicAdd(&acc[0], p); atomicAdd(&acc[1], n);
    atomicAdd(&acc[2], s2); atomicAdd(&acc[3], d);
  }
}

// ---------------- final combine ----------------
__global__ __launch_bounds__(256) void k_final(const int* __restrict__ targets,
    const int* __restrict__ epoch_p, int B, const float* acc, const unsigned* cnts,
    const unsigned* rowMinU, const unsigned* rowMaxU, float* out){
  int n0 = (int)cnts[0], n1 = (int)cnts[1], n2 = (int)cnts[2];
  float tsum = 0.f; float tcnt = 0.f;
  for (int i = threadIdx.x; i < B; i += 256){
    int t = targets[i];
    int nt = (t==0)?n0:((t==1)?n1:n2);
    if (nt - 1 > 0 && B - nt > 0){
      float mn = unmapf(rowMinU[i]);
      float mx = unmapf(rowMaxU[i]);
      float hp = sqrtf(fmaxf(2.f - 2.f*mn, 0.f));
      float hn = sqrtf(fmaxf(2.f - 2.f*mx, 0.f));
      float margin = 1.5f * ((t==1) ? 2.5f : 1.f);
      float tl = fmaxf(hp - hn + margin, 0.f);
      tsum += tl; tcnt += 1.f;
    }
  }
  #pragma unroll
  for (int off=32; off; off>>=1){ tsum += __shfl_xor(tsum, off); tcnt += __shfl_xor(tcnt, off); }
  __shared__ float sb[4][2];
  int wave = threadIdx.x>>6, lane = threadIdx.x&63;
  if (lane==0){ sb[wave][0]=tsum; sb[wave][1]=tcnt; }
  __syncthreads();
  if (threadIdx.x==0){
    float ts=0, tn=0;
    for (int w2=0;w2<4;w2++){ ts+=sb[w2][0]; tn+=sb[w2][1]; }
    float triplet = (tn > 0.f) ? ts / fmaxf(tn, 1.f) : 0.f;
    float pos=acc[0], neg=acc[1], semi=acc[2], diag=acc[3];
    float Bf = (float)B;
    float focal = acc[4] / Bf;
    float ce = acc[5] / acc[6];
    float boundary = acc[7] / (Bf + 1e-8f);
    float contrastive = (pos + neg + 4.f*semi) / (Bf*Bf + 1e-8f);
    long long npl = ((long long)n0*(n0-1) + (long long)n1*(n1-1) + (long long)n2*(n2-1))/2;
    float qsum = (pos - diag) * 0.5f;
    float q = qsum / (float)(npl > 0 ? npl : 1);
    if (n2 > 0) q *= (1.f + 2.5f * ((float)n2 / Bf));
    float quality = (npl > 0) ? q : 0.f;
    int ep = epoch_p[0];
    float er = (float)ep / 25.f;
    float ann = fminf(1.f, er*er);
    float evidential = acc[8]/Bf + ann*0.2f*acc[9]/Bf;
    float total = 0.4f*focal + 0.3f*ce + 0.15f*boundary
                + 0.1f*contrastive + 0.1f*triplet + 0.1f*quality + 0.1f*evidential;
    out[0] = total;
  }
}

extern "C" void kernel_launch(void* const* d_in, const int* in_sizes, int n_in,
                              void* d_out, int out_size, void* d_ws, size_t ws_size,
                              hipStream_t stream){
  const float* logits   = (const float*)d_in[0];
  const int*   targets  = (const int*)d_in[1];
  const float* features = (const float*)d_in[2];
  const float* alpha    = (const float*)d_in[3];
  const int*   epoch    = (const int*)d_in[4];
  const float* fa       = (const float*)d_in[5];
  const float* cw       = (const float*)d_in[6];
  int B = in_sizes[1];
  int D = in_sizes[2] / B;

  char* ws = (char*)d_ws;
  float*    acc     = (float*)ws;                         // 16 floats
  unsigned* cnts    = (unsigned*)(ws + 64);               // 3 uints
  unsigned* rowMinU = (unsigned*)(ws + 128);              // B uints
  unsigned* rowMaxU = (unsigned*)(ws + 128 + (size_t)B*4);// B uints
  __bf16*   fb      = (__bf16*)(ws + 128 + (size_t)B*8);  // B*D bf16

  k_init  <<<(B+255)/256, 256, 0, stream>>>(acc, cnts, rowMinU, rowMaxU, B);
  k_norm  <<<(B+3)/4,     256, 0, stream>>>(features, fb, B, D);
  k_sample<<<(B+255)/256, 256, 0, stream>>>(logits, targets, alpha, fa, cw, B, acc, cnts);
  int ntile = B/128;
  k_pairs <<<ntile*ntile, 256, 0, stream>>>(fb, targets, B, D, acc, rowMinU, rowMaxU);
  k_final <<<1, 256, 0, stream>>>(targets, epoch, B, acc, cnts, rowMinU, rowMaxU, (float*)d_out);
}

// Round 2
// 147.537 us; speedup vs baseline: 1.3763x; 1.3763x over previous
//
#include <hip/hip_runtime.h>
#include <hip/hip_bf16.h>
#include <cstdint>

#define NCLS 3

typedef __attribute__((ext_vector_type(8))) __bf16 bf8;
typedef __attribute__((ext_vector_type(4))) float f32x4;

#if defined(__has_builtin)
#if __has_builtin(__builtin_amdgcn_global_load_lds)
#define USE_GLL 1
#endif
#endif
#ifndef USE_GLL
#define USE_GLL 0
#endif

#if USE_GLL
__device__ __forceinline__ void gll16(const __bf16* g, __bf16* l){
  __builtin_amdgcn_global_load_lds(
      (const __attribute__((address_space(1))) void*)g,
      (__attribute__((address_space(3))) void*)l, 16, 0, 0);
}
#endif

// order-preserving float<->uint maps (for atomicMin/Max on sim values)
__device__ __forceinline__ unsigned mapf(float x){
  unsigned u = __float_as_uint(x);
  return (u & 0x80000000u) ? ~u : (u | 0x80000000u);
}
__device__ __forceinline__ float unmapf(unsigned u){
  return __uint_as_float((u & 0x80000000u) ? (u & 0x7FFFFFFFu) : ~u);
}

__device__ float digammaf_(float x){
  float r = 0.f;
  while (x < 6.f){ r -= 1.f/x; x += 1.f; }
  float inv = 1.f/x, inv2 = inv*inv;
  r += logf(x) - 0.5f*inv
     - inv2*(0.08333333333f - inv2*(0.008333333333f - inv2*0.003968253968f));
  return r;
}

// ---------------- init: zero accumulators, init row min/max ----------------
__global__ void k_init(float* acc, unsigned* cnts, unsigned* rowMinU, unsigned* rowMaxU, int B){
  int i = blockIdx.x*blockDim.x + threadIdx.x;
  if (i < B){ rowMinU[i] = 0xFFFFFFFFu; rowMaxU[i] = 0u; }
  if (i < 16) acc[i] = 0.f;
  if (i < NCLS) cnts[i] = 0u;
}

// ---------------- normalize features -> bf16 ----------------
__global__ __launch_bounds__(256) void k_norm(const float* __restrict__ feat,
                                              __bf16* __restrict__ fb, int B, int D){
  int wave = threadIdx.x >> 6, lane = threadIdx.x & 63;
  int row = blockIdx.x*4 + wave;
  if (row >= B) return;
  const float* src = feat + (size_t)row*D;
  float ss = 0.f;
  for (int c = lane*4; c < D; c += 64*4){
    float4 v = *(const float4*)(src + c);
    ss += v.x*v.x + v.y*v.y + v.z*v.z + v.w*v.w;
  }
  #pragma unroll
  for (int off=32; off; off>>=1) ss += __shfl_xor(ss, off);
  float inv = 1.f / fmaxf(sqrtf(ss), 1e-12f);
  __bf16* dst = fb + (size_t)row*D;
  for (int c = lane*8; c < D; c += 64*8){
    float4 v0 = *(const float4*)(src + c);
    float4 v1 = *(const float4*)(src + c + 4);
    bf8 o;
    o[0]=(__bf16)(v0.x*inv); o[1]=(__bf16)(v0.y*inv);
    o[2]=(__bf16)(v0.z*inv); o[3]=(__bf16)(v0.w*inv);
    o[4]=(__bf16)(v1.x*inv); o[5]=(__bf16)(v1.y*inv);
    o[6]=(__bf16)(v1.z*inv); o[7]=(__bf16)(v1.w*inv);
    *(bf8*)(dst + c) = o;
  }
}

// ---------------- per-sample losses (focal, wCE, boundary, evidential) -----
__global__ __launch_bounds__(256) void k_sample(const float* __restrict__ logits,
    const int* __restrict__ targets, const float* __restrict__ alpha,
    const float* __restrict__ fa, const float* __restrict__ cw,
    int B, float* acc, unsigned* cnts){
  int i = blockIdx.x*blockDim.x + threadIdx.x;
  float focal_i=0, ce_n=0, ce_d=0, bnd=0, lik=0, kl=0;
  int t = 0; bool active = i < B;
  if (active){
    float l0=logits[3*i], l1=logits[3*i+1], l2=logits[3*i+2];
    t = targets[i];
    float m = fmaxf(l0, fmaxf(l1,l2));
    float e0=expf(l0-m), e1=expf(l1-m), e2=expf(l2-m);
    float se = e0+e1+e2;
    float lse = m + logf(se);
    float lp0=l0-lse, lp1=l1-lse, lp2=l2-lse;
    float lpt = (t==0)?lp0:((t==1)?lp1:lp2);
    float nll = -lpt;
    float ce_ls = 0.9f*nll + 0.1f*(-(lp0+lp1+lp2)*(1.f/3.f));
    float pt = expf(-ce_ls);
    float om = 1.f - pt;
    focal_i = fa[t]*om*om*ce_ls;
    float w = cw[t];
    ce_n = w*nll; ce_d = w;
    float p0=e0/se, p1=e1/se, p2=e2/se;
    if (t==0)      bnd = p1 + 0.6f*p2;
    else if (t==2) bnd = p1 + 0.4f*p0;
    else           bnd = 4.5f*(1.f - p1 + 0.3f*(p0+p2));
    float a0=alpha[3*i], a1=alpha[3*i+1], a2=alpha[3*i+2];
    float S = a0+a1+a2 + 1e-8f;
    float at_ = (t==0)?a0:((t==1)?a1:a2);
    lik = digammaf_(S) - digammaf_(at_ + 1e-8f);
    float b0 = (t==0)?1.f:a0, b1 = (t==1)?1.f:a1, b2 = (t==2)?1.f:a2;
    float ats = b0+b1+b2 + 1e-8f;
    float psa = digammaf_(ats + 1e-8f);
    kl = lgammaf(ats)
       - (lgammaf(b0+1e-8f)+lgammaf(b1+1e-8f)+lgammaf(b2+1e-8f))
       + (b0-1.f)*(digammaf_(b0+1e-8f)-psa)
       + (b1-1.f)*(digammaf_(b1+1e-8f)-psa)
       + (b2-1.f)*(digammaf_(b2+1e-8f)-psa);
  }
  unsigned long long m0 = __ballot(active && t==0);
  unsigned long long m1 = __ballot(active && t==1);
  unsigned long long m2 = __ballot(active && t==2);
  #pragma unroll
  for (int off=32; off; off>>=1){
    focal_i += __shfl_xor(focal_i, off);
    ce_n    += __shfl_xor(ce_n, off);
    ce_d    += __shfl_xor(ce_d, off);
    bnd     += __shfl_xor(bnd, off);
    lik     += __shfl_xor(lik, off);
    kl      += __shfl_xor(kl, off);
  }
  if ((threadIdx.x & 63) == 0){
    atomicAdd(&acc[4], focal_i); atomicAdd(&acc[5], ce_n); atomicAdd(&acc[6], ce_d);
    atomicAdd(&acc[7], bnd);     atomicAdd(&acc[8], lik);  atomicAdd(&acc[9], kl);
    atomicAdd(&cnts[0], (unsigned)__popcll(m0));
    atomicAdd(&cnts[1], (unsigned)__popcll(m1));
    atomicAdd(&cnts[2], (unsigned)__popcll(m2));
  }
}

// ---------------- pair kernel: fused sim reductions via MFMA ----------------
// Triangular grid (by<=bx). 128x128 tile, LDS-staged (global_load_lds, width 16),
// XOR col-block swizzle -> 2-way-max bank aliasing on ds_read_b128 (free).
// Off-diag tiles: sums x2, plus per-COLUMN min/max (transpose contribution).
__global__ __launch_bounds__(256) void k_pairs(const __bf16* __restrict__ fb,
    const int* __restrict__ targets, int B, int D,
    float* acc, unsigned* rowMinU, unsigned* rowMaxU){
  __shared__ __bf16 sA[128*32];
  __shared__ __bf16 sB[128*32];
  __shared__ int sRT[128];
  __shared__ int sCT[128];
  __shared__ float sred[4][4];

  // decode triangular tile index -> (by, bx), by <= bx
  int t = blockIdx.x;
  int bx = (int)((sqrtf(8.f*(float)t + 1.f) - 1.f)*0.5f);
  while ((bx+1)*(bx+2)/2 <= t) bx++;
  while (bx*(bx+1)/2 > t) bx--;
  int by = t - bx*(bx+1)/2;
  bool isDiag = (by == bx);
  int rowBase = by*128, colBase = bx*128;

  int tid = threadIdx.x, lane = tid & 63, wave = tid >> 6;
  int wr = wave >> 1, wc = wave & 1;
  int quad = lane >> 4, l16 = lane & 15;

  if (tid < 128) sRT[tid] = targets[rowBase + tid];
  else           sCT[tid-128] = targets[colBase + tid - 128];

  // staging addresses: LDS element e = tid*8 + rnd*2048 maps to (row=e/32, cb=(e%32)/8)
  // global col-block = cb ^ ((row>>1)&3)  (swizzle)
  const __bf16* gA[2]; const __bf16* gB[2];
  __bf16* lA[2]; __bf16* lB[2];
  #pragma unroll
  for (int rnd=0; rnd<2; rnd++){
    int e = tid*8 + rnd*2048;
    int row = e >> 5;
    int cb = (e & 31) >> 3;
    int gcb = cb ^ ((row >> 1) & 3);
    gA[rnd] = fb + (size_t)(rowBase + row)*D + gcb*8;
    gB[rnd] = fb + (size_t)(colBase + row)*D + gcb*8;
#if USE_GLL
    lA[rnd] = sA + wave*512 + rnd*2048;   // wave-uniform base; HW adds lane*16B
    lB[rnd] = sB + wave*512 + rnd*2048;
#else
    lA[rnd] = sA + tid*8 + rnd*2048;
    lB[rnd] = sB + tid*8 + rnd*2048;
#endif
  }

  // fragment LDS offsets (elements), inverse of the swizzle
  int offA[4], offB[4];
  #pragma unroll
  for (int mi=0; mi<4; mi++){
    int R = wr*64 + mi*16 + l16;
    offA[mi] = R*32 + ((quad ^ ((R>>1)&3))*8);
  }
  #pragma unroll
  for (int ni=0; ni<4; ni++){
    int R = wc*64 + ni*16 + l16;
    offB[ni] = R*32 + ((quad ^ ((R>>1)&3))*8);
  }

  f32x4 C[4][4] = {};

  for (int k0=0; k0<D; k0+=32){
    __syncthreads();              // protect LDS from previous iter's readers
#if USE_GLL
    gll16(gA[0]+k0, lA[0]); gll16(gA[1]+k0, lA[1]);
    gll16(gB[0]+k0, lB[0]); gll16(gB[1]+k0, lB[1]);
#else
    *(bf8*)lA[0] = *(const bf8*)(gA[0]+k0);
    *(bf8*)lA[1] = *(const bf8*)(gA[1]+k0);
    *(bf8*)lB[0] = *(const bf8*)(gB[0]+k0);
    *(bf8*)lB[1] = *(const bf8*)(gB[1]+k0);
#endif
    __syncthreads();              // drains vmcnt (global_load_lds) + lgkm
    bf8 aF[4], bF[4];
    #pragma unroll
    for (int mi=0; mi<4; mi++) aF[mi] = *(const bf8*)(sA + offA[mi]);
    #pragma unroll
    for (int ni=0; ni<4; ni++) bF[ni] = *(const bf8*)(sB + offB[ni]);
    #pragma unroll
    for (int mi=0; mi<4; mi++)
      #pragma unroll
      for (int ni=0; ni<4; ni++)
        C[mi][ni] = __builtin_amdgcn_mfma_f32_16x16x32_bf16(aF[mi], bF[ni], C[mi][ni], 0,0,0);
  }

  // ---- fused epilogue ----
  int tcol[4];
  #pragma unroll
  for (int ni=0; ni<4; ni++) tcol[ni] = sCT[wc*64 + ni*16 + l16];

  float pos=0.f, neg=0.f, semi=0.f, diag=0.f;
  float cmin[4], cmax[4];
  #pragma unroll
  for (int ni=0; ni<4; ni++){ cmin[ni]=2.f; cmax[ni]=-2.f; }

  #pragma unroll
  for (int mi=0; mi<4; mi++){
    #pragma unroll
    for (int r=0; r<4; r++){
      int rl = wr*64 + mi*16 + quad*4 + r;
      int row = rowBase + rl;
      int tr = sRT[rl];
      float vmin = 2.f, vmax = -2.f;
      #pragma unroll
      for (int ni=0; ni<4; ni++){
        int col = colBase + wc*64 + ni*16 + l16;
        float s = C[mi][ni][r];
        if (tr == tcol[ni]){
          float om = 1.f - s;
          float q = om*om;
          pos += q;
          if (tr == 1) semi += q;
          if (row == col) diag += q;   // only possible on diagonal tiles
          else {
            vmin = fminf(vmin, s);
            cmin[ni] = fminf(cmin[ni], s);
          }
        } else {
          float c0 = fmaxf(s - 0.2f, 0.f);
          neg += c0*c0;
          vmax = fmaxf(vmax, s);
          cmax[ni] = fmaxf(cmax[ni], s);
        }
      }
      // row-direction reduce across the 16 lanes of this quad (share `row`)
      #pragma unroll
      for (int off=1; off<16; off<<=1){
        vmin = fminf(vmin, __shfl_xor(vmin, off));
        vmax = fmaxf(vmax, __shfl_xor(vmax, off));
      }
      if (l16 == 0){
        atomicMin(&rowMinU[row], mapf(vmin));
        atomicMax(&rowMaxU[row], mapf(vmax));
      }
    }
  }

  // column-direction (transpose) contribution for off-diagonal tiles
  if (!isDiag){
    #pragma unroll
    for (int ni=0; ni<4; ni++){
      float cn = cmin[ni], cx = cmax[ni];
      cn = fminf(cn, __shfl_xor(cn, 16)); cn = fminf(cn, __shfl_xor(cn, 32));
      cx = fmaxf(cx, __shfl_xor(cx, 16)); cx = fmaxf(cx, __shfl_xor(cx, 32));
      if (quad == 0){
        int col = colBase + wc*64 + ni*16 + l16;
        atomicMin(&rowMinU[col], mapf(cn));
        atomicMax(&rowMaxU[col], mapf(cx));
      }
    }
  }

  #pragma unroll
  for (int off=32; off; off>>=1){
    pos  += __shfl_xor(pos, off);
    neg  += __shfl_xor(neg, off);
    semi += __shfl_xor(semi, off);
    diag += __shfl_xor(diag, off);
  }
  if (lane == 0){ sred[wave][0]=pos; sred[wave][1]=neg; sred[wave][2]=semi; sred[wave][3]=diag; }
  __syncthreads();
  if (tid == 0){
    float fac = isDiag ? 1.f : 2.f;
    float p=0,n=0,s2=0,d=0;
    for (int w2=0; w2<4; w2++){ p+=sred[w2][0]; n+=sred[w2][1]; s2+=sred[w2][2]; d+=sred[w2][3]; }
    atomicAdd(&acc[0], p*fac); atomicAdd(&acc[1], n*fac);
    atomicAdd(&acc[2], s2*fac); atomicAdd(&acc[3], d);
  }
}

// ---------------- final combine ----------------
__global__ __launch_bounds__(256) void k_final(const int* __restrict__ targets,
    const int* __restrict__ epoch_p, int B, const float* acc, const unsigned* cnts,
    const unsigned* rowMinU, const unsigned* rowMaxU, float* out){
  int n0 = (int)cnts[0], n1 = (int)cnts[1], n2 = (int)cnts[2];
  float tsum = 0.f; float tcnt = 0.f;
  for (int i = threadIdx.x; i < B; i += 256){
    int t = targets[i];
    int nt = (t==0)?n0:((t==1)?n1:n2);
    if (nt - 1 > 0 && B - nt > 0){
      float mn = unmapf(rowMinU[i]);
      float mx = unmapf(rowMaxU[i]);
      float hp = sqrtf(fmaxf(2.f - 2.f*mn, 0.f));
      float hn = sqrtf(fmaxf(2.f - 2.f*mx, 0.f));
      float margin = 1.5f * ((t==1) ? 2.5f : 1.f);
      float tl = fmaxf(hp - hn + margin, 0.f);
      tsum += tl; tcnt += 1.f;
    }
  }
  #pragma unroll
  for (int off=32; off; off>>=1){ tsum += __shfl_xor(tsum, off); tcnt += __shfl_xor(tcnt, off); }
  __shared__ float sb[4][2];
  int wave = threadIdx.x>>6, lane = threadIdx.x&63;
  if (lane==0){ sb[wave][0]=tsum; sb[wave][1]=tcnt; }
  __syncthreads();
  if (threadIdx.x==0){
    float ts=0, tn=0;
    for (int w2=0;w2<4;w2++){ ts+=sb[w2][0]; tn+=sb[w2][1]; }
    float triplet = (tn > 0.f) ? ts / fmaxf(tn, 1.f) : 0.f;
    float pos=acc[0], neg=acc[1], semi=acc[2], diag=acc[3];
    float Bf = (float)B;
    float focal = acc[4] / Bf;
    float ce = acc[5] / acc[6];
    float boundary = acc[7] / (Bf + 1e-8f);
    float contrastive = (pos + neg + 4.f*semi) / (Bf*Bf + 1e-8f);
    long long npl = ((long long)n0*(n0-1) + (long long)n1*(n1-1) + (long long)n2*(n2-1))/2;
    float qsum = (pos - diag) * 0.5f;
    float q = qsum / (float)(npl > 0 ? npl : 1);
    if (n2 > 0) q *= (1.f + 2.5f * ((float)n2 / Bf));
    float quality = (npl > 0) ? q : 0.f;
    int ep = epoch_p[0];
    float er = (float)ep / 25.f;
    float ann = fminf(1.f, er*er);
    float evidential = acc[8]/Bf + ann*0.2f*acc[9]/Bf;
    float total = 0.4f*focal + 0.3f*ce + 0.15f*boundary
                + 0.1f*contrastive + 0.1f*triplet + 0.1f*quality + 0.1f*evidential;
    out[0] = total;
  }
}

extern "C" void kernel_launch(void* const* d_in, const int* in_sizes, int n_in,
                              void* d_out, int out_size, void* d_ws, size_t ws_size,
                              hipStream_t stream){
  const float* logits   = (const float*)d_in[0];
  const int*   targets  = (const int*)d_in[1];
  const float* features = (const float*)d_in[2];
  const float* alpha    = (const float*)d_in[3];
  const int*   epoch    = (const int*)d_in[4];
  const float* fa       = (const float*)d_in[5];
  const float* cw       = (const float*)d_in[6];
  int B = in_sizes[1];
  int D = in_sizes[2] / B;

  char* ws = (char*)d_ws;
  float*    acc     = (float*)ws;                         // 16 floats
  unsigned* cnts    = (unsigned*)(ws + 64);               // 3 uints
  unsigned* rowMinU = (unsigned*)(ws + 128);              // B uints
  unsigned* rowMaxU = (unsigned*)(ws + 128 + (size_t)B*4);// B uints
  __bf16*   fb      = (__bf16*)(ws + 128 + (size_t)B*8);  // B*D bf16

  k_init  <<<(B+255)/256, 256, 0, stream>>>(acc, cnts, rowMinU, rowMaxU, B);
  k_norm  <<<(B+3)/4,     256, 0, stream>>>(features, fb, B, D);
  k_sample<<<(B+255)/256, 256, 0, stream>>>(logits, targets, alpha, fa, cw, B, acc, cnts);
  int ntile = B/128;
  int nblk  = ntile*(ntile+1)/2;   // triangular: by <= bx
  k_pairs <<<nblk, 256, 0, stream>>>(fb, targets, B, D, acc, rowMinU, rowMaxU);
  k_final <<<1, 256, 0, stream>>>(targets, epoch, B, acc, cnts, rowMinU, rowMaxU, (float*)d_out);
}

// Round 3
// 138.067 us; speedup vs baseline: 1.4707x; 1.0686x over previous
//
#include <hip/hip_runtime.h>
#include <hip/hip_bf16.h>
#include <cstdint>

typedef __attribute__((ext_vector_type(8))) __bf16 bf8;
typedef __attribute__((ext_vector_type(4))) float f32x4;

#if defined(__has_builtin)
#if __has_builtin(__builtin_amdgcn_global_load_lds)
#define USE_GLL 1
#endif
#endif
#ifndef USE_GLL
#define USE_GLL 0
#endif

#if USE_GLL
__device__ __forceinline__ void gll16(const __bf16* g, __bf16* l){
  __builtin_amdgcn_global_load_lds(
      (const __attribute__((address_space(1))) void*)g,
      (__attribute__((address_space(3))) void*)l, 16, 0, 0);
}
#endif

// order-preserving float<->uint maps (for atomicMin/Max on sim values)
__device__ __forceinline__ unsigned mapf(float x){
  unsigned u = __float_as_uint(x);
  return (u & 0x80000000u) ? ~u : (u | 0x80000000u);
}
__device__ __forceinline__ float unmapf(unsigned u){
  return __uint_as_float((u & 0x80000000u) ? (u & 0x7FFFFFFFu) : ~u);
}

__device__ float digammaf_(float x){
  float r = 0.f;
  while (x < 6.f){ r -= 1.f/x; x += 1.f; }
  float inv = 1.f/x, inv2 = inv*inv;
  r += logf(x) - 0.5f*inv
     - inv2*(0.08333333333f - inv2*(0.008333333333f - inv2*0.003968253968f));
  return r;
}

// ============ k_prep: init + normalize->bf16 + per-sample losses ============
// grid = B/4 blocks of 256. Each block normalizes 4 rows (1 wave/row).
// Blocks [0, B/256): also init rowMin/Max for 256 rows and compute sample
// losses for 256 samples, writing PER-WAVE partials to psum/pcnt slots
// (each slot written exactly once -> no zero-init, no atomics).
// Block B/256: zeroes acc[0..15] (consumed by k_pairs atomics).
__global__ __launch_bounds__(256) void k_prep(const float* __restrict__ feat,
    __bf16* __restrict__ fb,
    const float* __restrict__ logits, const int* __restrict__ targets,
    const float* __restrict__ alpha,  const float* __restrict__ fa,
    const float* __restrict__ cw, int B, int D,
    float* __restrict__ psum, unsigned* __restrict__ pcnt,
    float* __restrict__ acc, unsigned* rowMinU, unsigned* rowMaxU){
  int bid = blockIdx.x, tid = threadIdx.x;
  int wave = tid >> 6, lane = tid & 63;

  // ---- normalize 4 rows ----
  int row = bid*4 + wave;
  if (row < B){
    const float* src = feat + (size_t)row*D;
    float ss = 0.f;
    for (int c = lane*4; c < D; c += 64*4){
      float4 v = *(const float4*)(src + c);
      ss += v.x*v.x + v.y*v.y + v.z*v.z + v.w*v.w;
    }
    #pragma unroll
    for (int off=32; off; off>>=1) ss += __shfl_xor(ss, off);
    float inv = 1.f / fmaxf(sqrtf(ss), 1e-12f);
    __bf16* dst = fb + (size_t)row*D;
    for (int c = lane*8; c < D; c += 64*8){
      float4 v0 = *(const float4*)(src + c);
      float4 v1 = *(const float4*)(src + c + 4);
      bf8 o;
      o[0]=(__bf16)(v0.x*inv); o[1]=(__bf16)(v0.y*inv);
      o[2]=(__bf16)(v0.z*inv); o[3]=(__bf16)(v0.w*inv);
      o[4]=(__bf16)(v1.x*inv); o[5]=(__bf16)(v1.y*inv);
      o[6]=(__bf16)(v1.z*inv); o[7]=(__bf16)(v1.w*inv);
      *(bf8*)(dst + c) = o;
    }
  }

  int SB = B >> 8;                  // B/256 sample blocks
  if (bid == SB && tid < 16) acc[tid] = 0.f;
  if (bid >= SB) return;

  // ---- init row min/max ----
  int i = bid*256 + tid;
  rowMinU[i] = 0xFFFFFFFFu; rowMaxU[i] = 0u;

  // ---- per-sample losses ----
  float l0=logits[3*i], l1=logits[3*i+1], l2=logits[3*i+2];
  int t = targets[i];
  float m = fmaxf(l0, fmaxf(l1,l2));
  float e0=expf(l0-m), e1=expf(l1-m), e2=expf(l2-m);
  float se = e0+e1+e2;
  float lse = m + logf(se);
  float lp0=l0-lse, lp1=l1-lse, lp2=l2-lse;
  float lpt = (t==0)?lp0:((t==1)?lp1:lp2);
  float nll = -lpt;
  float ce_ls = 0.9f*nll + 0.1f*(-(lp0+lp1+lp2)*(1.f/3.f));
  float pt = expf(-ce_ls);
  float om = 1.f - pt;
  float focal_i = fa[t]*om*om*ce_ls;
  float w = cw[t];
  float ce_n = w*nll, ce_d = w;
  float p0=e0/se, p1=e1/se, p2=e2/se;
  float bnd;
  if (t==0)      bnd = p1 + 0.6f*p2;
  else if (t==2) bnd = p1 + 0.4f*p0;
  else           bnd = 4.5f*(1.f - p1 + 0.3f*(p0+p2));
  float a0=alpha[3*i], a1=alpha[3*i+1], a2=alpha[3*i+2];
  float S = a0+a1+a2 + 1e-8f;
  float at_ = (t==0)?a0:((t==1)?a1:a2);
  float lik = digammaf_(S) - digammaf_(at_ + 1e-8f);
  float b0 = (t==0)?1.f:a0, b1 = (t==1)?1.f:a1, b2 = (t==2)?1.f:a2;
  float ats = b0+b1+b2 + 1e-8f;
  float psa = digammaf_(ats + 1e-8f);
  float kl = lgammaf(ats)
     - (lgammaf(b0+1e-8f)+lgammaf(b1+1e-8f)+lgammaf(b2+1e-8f))
     + (b0-1.f)*(digammaf_(b0+1e-8f)-psa)
     + (b1-1.f)*(digammaf_(b1+1e-8f)-psa)
     + (b2-1.f)*(digammaf_(b2+1e-8f)-psa);

  unsigned long long m0 = __ballot(t==0);
  unsigned long long m1 = __ballot(t==1);
  unsigned long long m2 = __ballot(t==2);
  #pragma unroll
  for (int off=32; off; off>>=1){
    focal_i += __shfl_xor(focal_i, off);
    ce_n    += __shfl_xor(ce_n, off);
    ce_d    += __shfl_xor(ce_d, off);
    bnd     += __shfl_xor(bnd, off);
    lik     += __shfl_xor(lik, off);
    kl      += __shfl_xor(kl, off);
  }
  if (lane == 0){
    int slot = bid*4 + wave;
    psum[slot*8+0]=focal_i; psum[slot*8+1]=ce_n; psum[slot*8+2]=ce_d;
    psum[slot*8+3]=bnd;     psum[slot*8+4]=lik;  psum[slot*8+5]=kl;
    pcnt[slot*4+0]=(unsigned)__popcll(m0);
    pcnt[slot*4+1]=(unsigned)__popcll(m1);
    pcnt[slot*4+2]=(unsigned)__popcll(m2);
  }
}

// ============ k_pairs: fused sim reductions via MFMA ============
// Triangular grid (by<=bx). 128x128 tile, BK=32, DOUBLE-BUFFERED LDS:
// single barrier per K-iter; prefetch (global_load_lds w16) for iter k+1
// issued right after the barrier, overlapped by iter k's ds_read+MFMA.
// XOR col-block swizzle (applied to GLOBAL src addr) -> 2-way bank aliasing.
__global__ __launch_bounds__(256) void k_pairs(const __bf16* __restrict__ fb,
    const int* __restrict__ targets, int B, int D,
    float* acc, unsigned* rowMinU, unsigned* rowMaxU){
  __shared__ __bf16 sA[2][4096];
  __shared__ __bf16 sB[2][4096];
  __shared__ int sRT[128];
  __shared__ int sCT[128];
  __shared__ float sred[4][4];

  // decode triangular tile index -> (by, bx), by <= bx
  int t = blockIdx.x;
  int bx = (int)((sqrtf(8.f*(float)t + 1.f) - 1.f)*0.5f);
  while ((bx+1)*(bx+2)/2 <= t) bx++;
  while (bx*(bx+1)/2 > t) bx--;
  int by = t - bx*(bx+1)/2;
  bool isDiag = (by == bx);
  int rowBase = by*128, colBase = bx*128;

  int tid = threadIdx.x, lane = tid & 63, wave = tid >> 6;
  int wr = wave >> 1, wc = wave & 1;
  int quad = lane >> 4, l16 = lane & 15;

  if (tid < 128) sRT[tid] = targets[rowBase + tid];
  else           sCT[tid-128] = targets[colBase + tid - 128];

  // staging: LDS elem e = tid*8 + r*2048 -> (row=e/32, cb=(e%32)/8);
  // global col-block = cb ^ ((row>>1)&3)   (swizzle on global src)
  const __bf16* gA[2]; const __bf16* gB[2];
  #pragma unroll
  for (int r=0; r<2; r++){
    int e = tid*8 + r*2048;
    int row = e >> 5;
    int cb = (e & 31) >> 3;
    int gcb = cb ^ ((row >> 1) & 3);
    gA[r] = fb + (size_t)(rowBase + row)*D + gcb*8;
    gB[r] = fb + (size_t)(colBase + row)*D + gcb*8;
  }
  int wofs = wave*512;   // wave-uniform LDS base (HW adds lane*16B)

  // fragment LDS offsets (elements), inverse swizzle
  int offA[4], offB[4];
  #pragma unroll
  for (int mi=0; mi<4; mi++){
    int R = wr*64 + mi*16 + l16;
    offA[mi] = R*32 + ((quad ^ ((R>>1)&3))*8);
  }
  #pragma unroll
  for (int ni=0; ni<4; ni++){
    int R = wc*64 + ni*16 + l16;
    offB[ni] = R*32 + ((quad ^ ((R>>1)&3))*8);
  }

  // preload k=0 into buffer 0
#if USE_GLL
  #pragma unroll
  for (int r=0; r<2; r++){
    gll16(gA[r], &sA[0][wofs + r*2048]);
    gll16(gB[r], &sB[0][wofs + r*2048]);
  }
#else
  #pragma unroll
  for (int r=0; r<2; r++){
    *(bf8*)&sA[0][tid*8 + r*2048] = *(const bf8*)gA[r];
    *(bf8*)&sB[0][tid*8 + r*2048] = *(const bf8*)gB[r];
  }
#endif

  f32x4 C[4][4] = {};
  int NIT = D/32;
  int cur = 0;

  for (int it=0; it<NIT; ++it){
    __syncthreads();             // drains vmcnt -> buf[cur] staged; prev readers done
    if (it+1 < NIT){
      int k0 = (it+1)*32;
      int nb = cur ^ 1;
#if USE_GLL
      #pragma unroll
      for (int r=0; r<2; r++){
        gll16(gA[r]+k0, &sA[nb][wofs + r*2048]);
        gll16(gB[r]+k0, &sB[nb][wofs + r*2048]);
      }
#else
      #pragma unroll
      for (int r=0; r<2; r++){
        *(bf8*)&sA[nb][tid*8 + r*2048] = *(const bf8*)(gA[r]+k0);
        *(bf8*)&sB[nb][tid*8 + r*2048] = *(const bf8*)(gB[r]+k0);
      }
#endif
    }
    bf8 aF[4], bF[4];
    #pragma unroll
    for (int mi=0; mi<4; mi++) aF[mi] = *(const bf8*)(&sA[cur][offA[mi]]);
    #pragma unroll
    for (int ni=0; ni<4; ni++) bF[ni] = *(const bf8*)(&sB[cur][offB[ni]]);
    #pragma unroll
    for (int mi=0; mi<4; mi++)
      #pragma unroll
      for (int ni=0; ni<4; ni++)
        C[mi][ni] = __builtin_amdgcn_mfma_f32_16x16x32_bf16(aF[mi], bF[ni], C[mi][ni], 0,0,0);
    cur ^= 1;
  }

  // ---- fused epilogue ----
  int tcol[4];
  #pragma unroll
  for (int ni=0; ni<4; ni++) tcol[ni] = sCT[wc*64 + ni*16 + l16];

  float pos=0.f, neg=0.f, semi=0.f, diag=0.f;
  float cmin[4], cmax[4];
  #pragma unroll
  for (int ni=0; ni<4; ni++){ cmin[ni]=2.f; cmax[ni]=-2.f; }

  #pragma unroll
  for (int mi=0; mi<4; mi++){
    #pragma unroll
    for (int r=0; r<4; r++){
      int rl = wr*64 + mi*16 + quad*4 + r;
      int row = rowBase + rl;
      int tr = sRT[rl];
      float vmin = 2.f, vmax = -2.f;
      #pragma unroll
      for (int ni=0; ni<4; ni++){
        int col = colBase + wc*64 + ni*16 + l16;
        float s = C[mi][ni][r];
        if (tr == tcol[ni]){
          float omv = 1.f - s;
          float q = omv*omv;
          pos += q;
          if (tr == 1) semi += q;
          if (row == col) diag += q;     // only possible on diagonal tiles
          else {
            vmin = fminf(vmin, s);
            cmin[ni] = fminf(cmin[ni], s);
          }
        } else {
          float c0 = fmaxf(s - 0.2f, 0.f);
          neg += c0*c0;
          vmax = fmaxf(vmax, s);
          cmax[ni] = fmaxf(cmax[ni], s);
        }
      }
      #pragma unroll
      for (int off=1; off<16; off<<=1){
        vmin = fminf(vmin, __shfl_xor(vmin, off));
        vmax = fmaxf(vmax, __shfl_xor(vmax, off));
      }
      if (l16 == 0){
        atomicMin(&rowMinU[row], mapf(vmin));
        atomicMax(&rowMaxU[row], mapf(vmax));
      }
    }
  }

  // column-direction (transpose) contribution for off-diagonal tiles
  if (!isDiag){
    #pragma unroll
    for (int ni=0; ni<4; ni++){
      float cn = cmin[ni], cx = cmax[ni];
      cn = fminf(cn, __shfl_xor(cn, 16)); cn = fminf(cn, __shfl_xor(cn, 32));
      cx = fmaxf(cx, __shfl_xor(cx, 16)); cx = fmaxf(cx, __shfl_xor(cx, 32));
      if (quad == 0){
        int col = colBase + wc*64 + ni*16 + l16;
        atomicMin(&rowMinU[col], mapf(cn));
        atomicMax(&rowMaxU[col], mapf(cx));
      }
    }
  }

  #pragma unroll
  for (int off=32; off; off>>=1){
    pos  += __shfl_xor(pos, off);
    neg  += __shfl_xor(neg, off);
    semi += __shfl_xor(semi, off);
    diag += __shfl_xor(diag, off);
  }
  if (lane == 0){ sred[wave][0]=pos; sred[wave][1]=neg; sred[wave][2]=semi; sred[wave][3]=diag; }
  __syncthreads();
  if (tid == 0){
    float fac = isDiag ? 1.f : 2.f;
    float p=0,n=0,s2=0,d=0;
    for (int w2=0; w2<4; w2++){ p+=sred[w2][0]; n+=sred[w2][1]; s2+=sred[w2][2]; d+=sred[w2][3]; }
    atomicAdd(&acc[0], p*fac); atomicAdd(&acc[1], n*fac);
    atomicAdd(&acc[2], s2*fac); atomicAdd(&acc[3], d);
  }
}

// ============ k_final: reduce wave slots + triplet + combine ============
__global__ __launch_bounds__(256) void k_final(const int* __restrict__ targets,
    const int* __restrict__ epoch_p, int B, int SB,
    const float* acc, const float* psum, const unsigned* pcnt,
    const unsigned* rowMinU, const unsigned* rowMaxU, float* out){
  __shared__ float tot[6];
  __shared__ unsigned cn[3];
  int tid = threadIdx.x;
  int nslots = SB*4;

  if (tid < 64){
    float v0=0,v1=0,v2=0,v3=0,v4=0,v5=0;
    int c0=0,c1=0,c2=0;
    for (int s=tid; s<nslots; s+=64){
      v0+=psum[s*8+0]; v1+=psum[s*8+1]; v2+=psum[s*8+2];
      v3+=psum[s*8+3]; v4+=psum[s*8+4]; v5+=psum[s*8+5];
      c0+=(int)pcnt[s*4+0]; c1+=(int)pcnt[s*4+1]; c2+=(int)pcnt[s*4+2];
    }
    #pragma unroll
    for (int off=32; off; off>>=1){
      v0+=__shfl_xor(v0,off); v1+=__shfl_xor(v1,off); v2+=__shfl_xor(v2,off);
      v3+=__shfl_xor(v3,off); v4+=__shfl_xor(v4,off); v5+=__shfl_xor(v5,off);
      c0+=__shfl_xor(c0,off); c1+=__shfl_xor(c1,off); c2+=__shfl_xor(c2,off);
    }
    if (tid == 0){
      tot[0]=v0; tot[1]=v1; tot[2]=v2; tot[3]=v3; tot[4]=v4; tot[5]=v5;
      cn[0]=(unsigned)c0; cn[1]=(unsigned)c1; cn[2]=(unsigned)c2;
    }
  }
  __syncthreads();
  int n0=(int)cn[0], n1=(int)cn[1], n2=(int)cn[2];

  float tsum = 0.f, tcnt = 0.f;
  for (int i = tid; i < B; i += 256){
    int t = targets[i];
    int nt = (t==0)?n0:((t==1)?n1:n2);
    if (nt - 1 > 0 && B - nt > 0){
      float mn = unmapf(rowMinU[i]);
      float mx = unmapf(rowMaxU[i]);
      float hp = sqrtf(fmaxf(2.f - 2.f*mn, 0.f));
      float hn = sqrtf(fmaxf(2.f - 2.f*mx, 0.f));
      float margin = 1.5f * ((t==1) ? 2.5f : 1.f);
      float tl = fmaxf(hp - hn + margin, 0.f);
      tsum += tl; tcnt += 1.f;
    }
  }
  #pragma unroll
  for (int off=32; off; off>>=1){ tsum += __shfl_xor(tsum, off); tcnt += __shfl_xor(tcnt, off); }
  __shared__ float sb[4][2];
  int wave = tid>>6, lane = tid&63;
  if (lane==0){ sb[wave][0]=tsum; sb[wave][1]=tcnt; }
  __syncthreads();
  if (tid==0){
    float ts=0, tn=0;
    for (int w2=0;w2<4;w2++){ ts+=sb[w2][0]; tn+=sb[w2][1]; }
    float triplet = (tn > 0.f) ? ts / fmaxf(tn, 1.f) : 0.f;
    float pos=acc[0], neg=acc[1], semi=acc[2], diag=acc[3];
    float Bf = (float)B;
    float focal = tot[0] / Bf;
    float ce = tot[1] / tot[2];
    float boundary = tot[3] / (Bf + 1e-8f);
    float contrastive = (pos + neg + 4.f*semi) / (Bf*Bf + 1e-8f);
    long long npl = ((long long)n0*(n0-1) + (long long)n1*(n1-1) + (long long)n2*(n2-1))/2;
    float qsum = (pos - diag) * 0.5f;
    float q = qsum / (float)(npl > 0 ? npl : 1);
    if (n2 > 0) q *= (1.f + 2.5f * ((float)n2 / Bf));
    float quality = (npl > 0) ? q : 0.f;
    int ep = epoch_p[0];
    float er = (float)ep / 25.f;
    float ann = fminf(1.f, er*er);
    float evidential = tot[4]/Bf + ann*0.2f*tot[5]/Bf;
    float total = 0.4f*focal + 0.3f*ce + 0.15f*boundary
                + 0.1f*contrastive + 0.1f*triplet + 0.1f*quality + 0.1f*evidential;
    out[0] = total;
  }
}

extern "C" void kernel_launch(void* const* d_in, const int* in_sizes, int n_in,
                              void* d_out, int out_size, void* d_ws, size_t ws_size,
                              hipStream_t stream){
  const float* logits   = (const float*)d_in[0];
  const int*   targets  = (const int*)d_in[1];
  const float* features = (const float*)d_in[2];
  const float* alpha    = (const float*)d_in[3];
  const int*   epoch    = (const int*)d_in[4];
  const float* fa       = (const float*)d_in[5];
  const float* cw       = (const float*)d_in[6];
  int B = in_sizes[1];
  int D = in_sizes[2] / B;
  int SB = B >> 8;

  char* ws = (char*)d_ws;
  float*    acc     = (float*)ws;                           // 16 floats
  unsigned* pcnt    = (unsigned*)(ws + 128);                // SB*4*4 uints
  float*    psum    = (float*)(ws + 128 + (size_t)SB*64);   // SB*4*8 floats
  unsigned* rowMinU = (unsigned*)(ws + 4096);
  unsigned* rowMaxU = (unsigned*)(ws + 4096 + (size_t)B*4);
  __bf16*   fb      = (__bf16*)(ws + 4096 + (size_t)B*8);

  k_prep <<<B/4, 256, 0, stream>>>(features, fb, logits, targets, alpha, fa, cw,
                                   B, D, psum, pcnt, acc, rowMinU, rowMaxU);
  int ntile = B/128;
  int nblk  = ntile*(ntile+1)/2;   // triangular: by <= bx
  k_pairs<<<nblk, 256, 0, stream>>>(fb, targets, B, D, acc, rowMinU, rowMaxU);
  k_final<<<1, 256, 0, stream>>>(targets, epoch, B, SB, acc, psum, pcnt,
                                 rowMinU, rowMaxU, (float*)d_out);
}

// Round 4
// 129.400 us; speedup vs baseline: 1.5693x; 1.0670x over previous
//
#include <hip/hip_runtime.h>
#include <hip/hip_bf16.h>
#include <cstdint>

typedef __attribute__((ext_vector_type(8))) __bf16 bf8;
typedef __attribute__((ext_vector_type(4))) float f32x4;

#if defined(__has_builtin)
#if __has_builtin(__builtin_amdgcn_global_load_lds)
#define USE_GLL 1
#endif
#endif
#ifndef USE_GLL
#define USE_GLL 0
#endif

#if USE_GLL
__device__ __forceinline__ void gll16(const __bf16* g, __bf16* l){
  __builtin_amdgcn_global_load_lds(
      (const __attribute__((address_space(1))) void*)g,
      (__attribute__((address_space(3))) void*)l, 16, 0, 0);
}
#endif

// order-preserving float<->uint maps (for atomicMin/Max on sim values)
__device__ __forceinline__ unsigned mapf(float x){
  unsigned u = __float_as_uint(x);
  return (u & 0x80000000u) ? ~u : (u | 0x80000000u);
}
__device__ __forceinline__ float unmapf(unsigned u){
  return __uint_as_float((u & 0x80000000u) ? (u & 0x7FFFFFFFu) : ~u);
}

__device__ float digammaf_(float x){
  float r = 0.f;
  while (x < 6.f){ r -= 1.f/x; x += 1.f; }
  float inv = 1.f/x, inv2 = inv*inv;
  r += logf(x) - 0.5f*inv
     - inv2*(0.08333333333f - inv2*(0.008333333333f - inv2*0.003968253968f));
  return r;
}

// ============ k_prep: init + normalize->bf16 + per-sample losses ============
__global__ __launch_bounds__(256) void k_prep(const float* __restrict__ feat,
    __bf16* __restrict__ fb,
    const float* __restrict__ logits, const int* __restrict__ targets,
    const float* __restrict__ alpha,  const float* __restrict__ fa,
    const float* __restrict__ cw, int B, int D,
    float* __restrict__ psum, unsigned* __restrict__ pcnt,
    unsigned* rowMinU, unsigned* rowMaxU){
  int bid = blockIdx.x, tid = threadIdx.x;
  int wave = tid >> 6, lane = tid & 63;

  // ---- normalize 4 rows (1 wave/row) ----
  int row = bid*4 + wave;
  if (row < B){
    const float* src = feat + (size_t)row*D;
    float ss = 0.f;
    for (int c = lane*4; c < D; c += 64*4){
      float4 v = *(const float4*)(src + c);
      ss += v.x*v.x + v.y*v.y + v.z*v.z + v.w*v.w;
    }
    #pragma unroll
    for (int off=32; off; off>>=1) ss += __shfl_xor(ss, off);
    float inv = 1.f / fmaxf(sqrtf(ss), 1e-12f);
    __bf16* dst = fb + (size_t)row*D;
    for (int c = lane*8; c < D; c += 64*8){
      float4 v0 = *(const float4*)(src + c);
      float4 v1 = *(const float4*)(src + c + 4);
      bf8 o;
      o[0]=(__bf16)(v0.x*inv); o[1]=(__bf16)(v0.y*inv);
      o[2]=(__bf16)(v0.z*inv); o[3]=(__bf16)(v0.w*inv);
      o[4]=(__bf16)(v1.x*inv); o[5]=(__bf16)(v1.y*inv);
      o[6]=(__bf16)(v1.z*inv); o[7]=(__bf16)(v1.w*inv);
      *(bf8*)(dst + c) = o;
    }
  }

  int SB = B >> 8;                  // B/256 sample blocks
  if (bid >= SB) return;

  // ---- init row min/max ----
  int i = bid*256 + tid;
  rowMinU[i] = 0xFFFFFFFFu; rowMaxU[i] = 0u;

  // ---- per-sample losses ----
  float l0=logits[3*i], l1=logits[3*i+1], l2=logits[3*i+2];
  int t = targets[i];
  float m = fmaxf(l0, fmaxf(l1,l2));
  float e0=expf(l0-m), e1=expf(l1-m), e2=expf(l2-m);
  float se = e0+e1+e2;
  float lse = m + logf(se);
  float lp0=l0-lse, lp1=l1-lse, lp2=l2-lse;
  float lpt = (t==0)?lp0:((t==1)?lp1:lp2);
  float nll = -lpt;
  float ce_ls = 0.9f*nll + 0.1f*(-(lp0+lp1+lp2)*(1.f/3.f));
  float pt = expf(-ce_ls);
  float om = 1.f - pt;
  float focal_i = fa[t]*om*om*ce_ls;
  float w = cw[t];
  float ce_n = w*nll, ce_d = w;
  float p0=e0/se, p1=e1/se, p2=e2/se;
  float bnd;
  if (t==0)      bnd = p1 + 0.6f*p2;
  else if (t==2) bnd = p1 + 0.4f*p0;
  else           bnd = 4.5f*(1.f - p1 + 0.3f*(p0+p2));
  float a0=alpha[3*i], a1=alpha[3*i+1], a2=alpha[3*i+2];
  float S = a0+a1+a2 + 1e-8f;
  float at_ = (t==0)?a0:((t==1)?a1:a2);
  float lik = digammaf_(S) - digammaf_(at_ + 1e-8f);
  float b0 = (t==0)?1.f:a0, b1 = (t==1)?1.f:a1, b2 = (t==2)?1.f:a2;
  float ats = b0+b1+b2 + 1e-8f;
  float psa = digammaf_(ats + 1e-8f);
  float kl = lgammaf(ats)
     - (lgammaf(b0+1e-8f)+lgammaf(b1+1e-8f)+lgammaf(b2+1e-8f))
     + (b0-1.f)*(digammaf_(b0+1e-8f)-psa)
     + (b1-1.f)*(digammaf_(b1+1e-8f)-psa)
     + (b2-1.f)*(digammaf_(b2+1e-8f)-psa);

  unsigned long long m0 = __ballot(t==0);
  unsigned long long m1 = __ballot(t==1);
  unsigned long long m2 = __ballot(t==2);
  #pragma unroll
  for (int off=32; off; off>>=1){
    focal_i += __shfl_xor(focal_i, off);
    ce_n    += __shfl_xor(ce_n, off);
    ce_d    += __shfl_xor(ce_d, off);
    bnd     += __shfl_xor(bnd, off);
    lik     += __shfl_xor(lik, off);
    kl      += __shfl_xor(kl, off);
  }
  if (lane == 0){
    int slot = bid*4 + wave;
    psum[slot*8+0]=focal_i; psum[slot*8+1]=ce_n; psum[slot*8+2]=ce_d;
    psum[slot*8+3]=bnd;     psum[slot*8+4]=lik;  psum[slot*8+5]=kl;
    pcnt[slot*4+0]=(unsigned)__popcll(m0);
    pcnt[slot*4+1]=(unsigned)__popcll(m1);
    pcnt[slot*4+2]=(unsigned)__popcll(m2);
  }
}

// ============ k_pairs: 64x64 tiles, triangular grid, MFMA + fused epilogue ====
// 2080 blocks (T=64): ~6-8 blocks/CU resident -> TLP hides the barrier drain.
// 4 waves, each a 32x32 quadrant (2x2 of 16x16x32 MFMA). Double-buffered LDS,
// XOR col-block swizzle on global src (0 bank conflicts, rounds 2/3 measured).
// Block-level sums -> per-block slots (no same-line atomic contention).
__global__ __launch_bounds__(256, 6) void k_pairs(const __bf16* __restrict__ fb,
    const int* __restrict__ targets, int B, int D,
    float* __restrict__ pairPart, unsigned* rowMinU, unsigned* rowMaxU){
  __shared__ __bf16 sA[2][2048];
  __shared__ __bf16 sB[2][2048];
  __shared__ int sRT[64];
  __shared__ int sCT[64];
  __shared__ float sred[4][4];

  // decode triangular tile index -> (by, bx), by <= bx
  int t = blockIdx.x;
  int bx = (int)((sqrtf(8.f*(float)t + 1.f) - 1.f)*0.5f);
  while ((bx+1)*(bx+2)/2 <= t) bx++;
  while (bx*(bx+1)/2 > t) bx--;
  int by = t - bx*(bx+1)/2;
  bool isDiag = (by == bx);
  int rowBase = by*64, colBase = bx*64;

  int tid = threadIdx.x, lane = tid & 63, wave = tid >> 6;
  int wr = wave >> 1, wc = wave & 1;
  int quad = lane >> 4, l16 = lane & 15;

  if (tid < 64)       sRT[tid] = targets[rowBase + tid];
  else if (tid < 128) sCT[tid-64] = targets[colBase + tid - 64];

  // staging: LDS elem e = tid*8 -> row=tid>>2, cb=tid&3; global cb swizzled
  int srow = tid >> 2;
  int scb  = (tid & 3) ^ ((srow >> 1) & 3);
  const __bf16* gA = fb + (size_t)(rowBase + srow)*D + scb*8;
  const __bf16* gB = fb + (size_t)(colBase + srow)*D + scb*8;
  int wofs = wave*512;            // wave-uniform LDS base (HW adds lane*16B)

  // fragment LDS offsets (elements), inverse swizzle
  int offA[2], offB[2];
  #pragma unroll
  for (int mi=0; mi<2; mi++){
    int R = wr*32 + mi*16 + l16;
    offA[mi] = R*32 + ((quad ^ ((R>>1)&3))*8);
  }
  #pragma unroll
  for (int ni=0; ni<2; ni++){
    int R = wc*32 + ni*16 + l16;
    offB[ni] = R*32 + ((quad ^ ((R>>1)&3))*8);
  }

  f32x4 C[2][2] = {};
  int NIT = D/32;   // 16

#if USE_GLL
  #define STAGE(buf, k0) do{ gll16(gA + (k0), &sA[buf][wofs]); \
                             gll16(gB + (k0), &sB[buf][wofs]); }while(0)
#else
  #define STAGE(buf, k0) do{ *(bf8*)&sA[buf][tid*8] = *(const bf8*)(gA + (k0)); \
                             *(bf8*)&sB[buf][tid*8] = *(const bf8*)(gB + (k0)); }while(0)
#endif

  STAGE(0, 0);

  #define COMPUTE(buf) do{ \
    bf8 aF0 = *(const bf8*)(&sA[buf][offA[0]]); \
    bf8 aF1 = *(const bf8*)(&sA[buf][offA[1]]); \
    bf8 bF0 = *(const bf8*)(&sB[buf][offB[0]]); \
    bf8 bF1 = *(const bf8*)(&sB[buf][offB[1]]); \
    C[0][0] = __builtin_amdgcn_mfma_f32_16x16x32_bf16(aF0, bF0, C[0][0], 0,0,0); \
    C[0][1] = __builtin_amdgcn_mfma_f32_16x16x32_bf16(aF0, bF1, C[0][1], 0,0,0); \
    C[1][0] = __builtin_amdgcn_mfma_f32_16x16x32_bf16(aF1, bF0, C[1][0], 0,0,0); \
    C[1][1] = __builtin_amdgcn_mfma_f32_16x16x32_bf16(aF1, bF1, C[1][1], 0,0,0); \
  }while(0)

  for (int it=0; it<NIT; it+=2){
    __syncthreads();
    STAGE(1, (it+1)*32);
    COMPUTE(0);
    __syncthreads();
    if (it+2 < NIT) STAGE(0, (it+2)*32);
    COMPUTE(1);
  }

  // ---- fused epilogue ----
  int tcol[2];
  #pragma unroll
  for (int ni=0; ni<2; ni++) tcol[ni] = sCT[wc*32 + ni*16 + l16];

  float pos=0.f, neg=0.f, semi=0.f, diag=0.f;
  float cmin[2], cmax[2];
  #pragma unroll
  for (int ni=0; ni<2; ni++){ cmin[ni]=2.f; cmax[ni]=-2.f; }

  #pragma unroll
  for (int mi=0; mi<2; mi++){
    #pragma unroll
    for (int r=0; r<4; r++){
      int rl = wr*32 + mi*16 + quad*4 + r;
      int row = rowBase + rl;
      int tr = sRT[rl];
      float vmin = 2.f, vmax = -2.f;
      #pragma unroll
      for (int ni=0; ni<2; ni++){
        int col = colBase + wc*32 + ni*16 + l16;
        float s = C[mi][ni][r];
        if (tr == tcol[ni]){
          float omv = 1.f - s;
          float q = omv*omv;
          pos += q;
          if (tr == 1) semi += q;
          if (row == col) diag += q;     // only possible on diagonal tiles
          else {
            vmin = fminf(vmin, s);
            cmin[ni] = fminf(cmin[ni], s);
          }
        } else {
          float c0 = fmaxf(s - 0.2f, 0.f);
          neg += c0*c0;
          vmax = fmaxf(vmax, s);
          cmax[ni] = fmaxf(cmax[ni], s);
        }
      }
      #pragma unroll
      for (int off=1; off<16; off<<=1){
        vmin = fminf(vmin, __shfl_xor(vmin, off));
        vmax = fmaxf(vmax, __shfl_xor(vmax, off));
      }
      if (l16 == 0){
        atomicMin(&rowMinU[row], mapf(vmin));
        atomicMax(&rowMaxU[row], mapf(vmax));
      }
    }
  }

  // column-direction (transpose) contribution for off-diagonal tiles
  if (!isDiag){
    #pragma unroll
    for (int ni=0; ni<2; ni++){
      float cn = cmin[ni], cx = cmax[ni];
      cn = fminf(cn, __shfl_xor(cn, 16)); cn = fminf(cn, __shfl_xor(cn, 32));
      cx = fmaxf(cx, __shfl_xor(cx, 16)); cx = fmaxf(cx, __shfl_xor(cx, 32));
      if (quad == 0){
        int col = colBase + wc*32 + ni*16 + l16;
        atomicMin(&rowMinU[col], mapf(cn));
        atomicMax(&rowMaxU[col], mapf(cx));
      }
    }
  }

  #pragma unroll
  for (int off=32; off; off>>=1){
    pos  += __shfl_xor(pos, off);
    neg  += __shfl_xor(neg, off);
    semi += __shfl_xor(semi, off);
    diag += __shfl_xor(diag, off);
  }
  if (lane == 0){ sred[wave][0]=pos; sred[wave][1]=neg; sred[wave][2]=semi; sred[wave][3]=diag; }
  __syncthreads();
  if (tid == 0){
    float fac = isDiag ? 1.f : 2.f;
    float p=0,n=0,s2=0,d=0;
    for (int w2=0; w2<4; w2++){ p+=sred[w2][0]; n+=sred[w2][1]; s2+=sred[w2][2]; d+=sred[w2][3]; }
    pairPart[blockIdx.x*4+0] = p*fac;
    pairPart[blockIdx.x*4+1] = n*fac;
    pairPart[blockIdx.x*4+2] = s2*fac;
    pairPart[blockIdx.x*4+3] = d;
  }
}

// ============ k_final: reduce slots + triplet + combine ============
__global__ __launch_bounds__(256) void k_final(const int* __restrict__ targets,
    const int* __restrict__ epoch_p, int B, int SB, int nblk,
    const float* __restrict__ pairPart, const float* __restrict__ psum,
    const unsigned* __restrict__ pcnt,
    const unsigned* rowMinU, const unsigned* rowMaxU, float* out){
  __shared__ float tot[6];
  __shared__ unsigned cn[3];
  __shared__ float ptot[4];
  int tid = threadIdx.x;
  int nslots = SB*4;
  int wave = tid>>6, lane = tid&63;

  // reduce per-sample partials (wave 0) -- small
  if (tid < 64){
    float v0=0,v1=0,v2=0,v3=0,v4=0,v5=0;
    int c0=0,c1=0,c2=0;
    for (int s=tid; s<nslots; s+=64){
      v0+=psum[s*8+0]; v1+=psum[s*8+1]; v2+=psum[s*8+2];
      v3+=psum[s*8+3]; v4+=psum[s*8+4]; v5+=psum[s*8+5];
      c0+=(int)pcnt[s*4+0]; c1+=(int)pcnt[s*4+1]; c2+=(int)pcnt[s*4+2];
    }
    #pragma unroll
    for (int off=32; off; off>>=1){
      v0+=__shfl_xor(v0,off); v1+=__shfl_xor(v1,off); v2+=__shfl_xor(v2,off);
      v3+=__shfl_xor(v3,off); v4+=__shfl_xor(v4,off); v5+=__shfl_xor(v5,off);
      c0+=__shfl_xor(c0,off); c1+=__shfl_xor(c1,off); c2+=__shfl_xor(c2,off);
    }
    if (tid == 0){
      tot[0]=v0; tot[1]=v1; tot[2]=v2; tot[3]=v3; tot[4]=v4; tot[5]=v5;
      cn[0]=(unsigned)c0; cn[1]=(unsigned)c1; cn[2]=(unsigned)c2;
    }
  }

  // reduce pair partials (all 256 threads)
  {
    float p=0,n=0,s2=0,d=0;
    for (int s=tid; s<nblk; s+=256){
      p += pairPart[s*4+0]; n += pairPart[s*4+1];
      s2+= pairPart[s*4+2]; d += pairPart[s*4+3];
    }
    #pragma unroll
    for (int off=32; off; off>>=1){
      p+=__shfl_xor(p,off); n+=__shfl_xor(n,off);
      s2+=__shfl_xor(s2,off); d+=__shfl_xor(d,off);
    }
    __shared__ float pw[4][4];
    if (lane==0){ pw[wave][0]=p; pw[wave][1]=n; pw[wave][2]=s2; pw[wave][3]=d; }
    __syncthreads();
    if (tid==0){
      float a=0,b=0,c=0,e=0;
      for (int w2=0; w2<4; w2++){ a+=pw[w2][0]; b+=pw[w2][1]; c+=pw[w2][2]; e+=pw[w2][3]; }
      ptot[0]=a; ptot[1]=b; ptot[2]=c; ptot[3]=e;
    }
  }
  __syncthreads();
  int n0=(int)cn[0], n1=(int)cn[1], n2=(int)cn[2];

  float tsum = 0.f, tcnt = 0.f;
  for (int i = tid; i < B; i += 256){
    int t = targets[i];
    int nt = (t==0)?n0:((t==1)?n1:n2);
    if (nt - 1 > 0 && B - nt > 0){
      float mn = unmapf(rowMinU[i]);
      float mx = unmapf(rowMaxU[i]);
      float hp = sqrtf(fmaxf(2.f - 2.f*mn, 0.f));
      float hn = sqrtf(fmaxf(2.f - 2.f*mx, 0.f));
      float margin = 1.5f * ((t==1) ? 2.5f : 1.f);
      float tl = fmaxf(hp - hn + margin, 0.f);
      tsum += tl; tcnt += 1.f;
    }
  }
  #pragma unroll
  for (int off=32; off; off>>=1){ tsum += __shfl_xor(tsum, off); tcnt += __shfl_xor(tcnt, off); }
  __shared__ float sb[4][2];
  if (lane==0){ sb[wave][0]=tsum; sb[wave][1]=tcnt; }
  __syncthreads();
  if (tid==0){
    float ts=0, tn=0;
    for (int w2=0;w2<4;w2++){ ts+=sb[w2][0]; tn+=sb[w2][1]; }
    float triplet = (tn > 0.f) ? ts / fmaxf(tn, 1.f) : 0.f;
    float pos=ptot[0], neg=ptot[1], semi=ptot[2], diag=ptot[3];
    float Bf = (float)B;
    float focal = tot[0] / Bf;
    float ce = tot[1] / tot[2];
    float boundary = tot[3] / (Bf + 1e-8f);
    float contrastive = (pos + neg + 4.f*semi) / (Bf*Bf + 1e-8f);
    long long npl = ((long long)n0*(n0-1) + (long long)n1*(n1-1) + (long long)n2*(n2-1))/2;
    float qsum = (pos - diag) * 0.5f;
    float q = qsum / (float)(npl > 0 ? npl : 1);
    if (n2 > 0) q *= (1.f + 2.5f * ((float)n2 / Bf));
    float quality = (npl > 0) ? q : 0.f;
    int ep = epoch_p[0];
    float er = (float)ep / 25.f;
    float ann = fminf(1.f, er*er);
    float evidential = tot[4]/Bf + ann*0.2f*tot[5]/Bf;
    float total = 0.4f*focal + 0.3f*ce + 0.15f*boundary
                + 0.1f*contrastive + 0.1f*triplet + 0.1f*quality + 0.1f*evidential;
    out[0] = total;
  }
}

extern "C" void kernel_launch(void* const* d_in, const int* in_sizes, int n_in,
                              void* d_out, int out_size, void* d_ws, size_t ws_size,
                              hipStream_t stream){
  const float* logits   = (const float*)d_in[0];
  const int*   targets  = (const int*)d_in[1];
  const float* features = (const float*)d_in[2];
  const float* alpha    = (const float*)d_in[3];
  const int*   epoch    = (const int*)d_in[4];
  const float* fa       = (const float*)d_in[5];
  const float* cw       = (const float*)d_in[6];
  int B = in_sizes[1];
  int D = in_sizes[2] / B;
  int SB = B >> 8;
  int T  = B / 64;
  int nblk = T*(T+1)/2;            // triangular: by <= bx

  char* ws = (char*)d_ws;
  unsigned* pcnt     = (unsigned*)(ws);                       // SB*4*4 u32
  float*    psum     = (float*)(ws + 16384);                  // SB*4*8 f32
  float*    pairPart = (float*)(ws + 32768);                  // nblk*4 f32 (~33KB)
  unsigned* rowMinU  = (unsigned*)(ws + 131072);
  unsigned* rowMaxU  = (unsigned*)(ws + 131072 + (size_t)B*4);
  __bf16*   fb       = (__bf16*)(ws + 131072 + (size_t)B*8);

  k_prep <<<B/4, 256, 0, stream>>>(features, fb, logits, targets, alpha, fa, cw,
                                   B, D, psum, pcnt, rowMinU, rowMaxU);
  k_pairs<<<nblk, 256, 0, stream>>>(fb, targets, B, D, pairPart, rowMinU, rowMaxU);
  k_final<<<1, 256, 0, stream>>>(targets, epoch, B, SB, nblk, pairPart, psum, pcnt,
                                 rowMinU, rowMaxU, (float*)d_out);
}

// Round 5
// 127.786 us; speedup vs baseline: 1.5891x; 1.0126x over previous
//
#include <hip/hip_runtime.h>
#include <hip/hip_bf16.h>
#include <cstdint>

typedef __attribute__((ext_vector_type(8))) __bf16 bf8;
typedef __attribute__((ext_vector_type(4))) float f32x4;

#if defined(__has_builtin)
#if __has_builtin(__builtin_amdgcn_global_load_lds)
#define USE_GLL 1
#endif
#endif
#ifndef USE_GLL
#define USE_GLL 0
#endif

#if USE_GLL
__device__ __forceinline__ void gll16(const __bf16* g, __bf16* l){
  __builtin_amdgcn_global_load_lds(
      (const __attribute__((address_space(1))) void*)g,
      (__attribute__((address_space(3))) void*)l, 16, 0, 0);
}
#endif

// order-preserving float<->uint maps (for atomicMin/Max on sim values)
__device__ __forceinline__ unsigned mapf(float x){
  unsigned u = __float_as_uint(x);
  return (u & 0x80000000u) ? ~u : (u | 0x80000000u);
}
__device__ __forceinline__ float unmapf(unsigned u){
  return __uint_as_float((u & 0x80000000u) ? (u & 0x7FFFFFFFu) : ~u);
}

__device__ float digammaf_(float x){
  float r = 0.f;
  while (x < 6.f){ r -= 1.f/x; x += 1.f; }
  float inv = 1.f/x, inv2 = inv*inv;
  r += logf(x) - 0.5f*inv
     - inv2*(0.08333333333f - inv2*(0.008333333333f - inv2*0.003968253968f));
  return r;
}

// ============ k_prep: init + normalize->bf16 + per-sample losses ============
__global__ __launch_bounds__(256) void k_prep(const float* __restrict__ feat,
    __bf16* __restrict__ fb,
    const float* __restrict__ logits, const int* __restrict__ targets,
    const float* __restrict__ alpha,  const float* __restrict__ fa,
    const float* __restrict__ cw, int B, int D,
    float* __restrict__ psum, unsigned* __restrict__ pcnt,
    unsigned* rowMinU, unsigned* rowMaxU){
  int bid = blockIdx.x, tid = threadIdx.x;
  int wave = tid >> 6, lane = tid & 63;

  // ---- normalize 4 rows (1 wave/row) ----
  int row = bid*4 + wave;
  if (row < B){
    const float* src = feat + (size_t)row*D;
    float ss = 0.f;
    for (int c = lane*4; c < D; c += 64*4){
      float4 v = *(const float4*)(src + c);
      ss += v.x*v.x + v.y*v.y + v.z*v.z + v.w*v.w;
    }
    #pragma unroll
    for (int off=32; off; off>>=1) ss += __shfl_xor(ss, off);
    float inv = 1.f / fmaxf(sqrtf(ss), 1e-12f);
    __bf16* dst = fb + (size_t)row*D;
    for (int c = lane*8; c < D; c += 64*8){
      float4 v0 = *(const float4*)(src + c);
      float4 v1 = *(const float4*)(src + c + 4);
      bf8 o;
      o[0]=(__bf16)(v0.x*inv); o[1]=(__bf16)(v0.y*inv);
      o[2]=(__bf16)(v0.z*inv); o[3]=(__bf16)(v0.w*inv);
      o[4]=(__bf16)(v1.x*inv); o[5]=(__bf16)(v1.y*inv);
      o[6]=(__bf16)(v1.z*inv); o[7]=(__bf16)(v1.w*inv);
      *(bf8*)(dst + c) = o;
    }
  }

  int SB = B >> 8;                  // B/256 sample blocks
  if (bid >= SB) return;

  // ---- init row min/max ----
  int i = bid*256 + tid;
  rowMinU[i] = 0xFFFFFFFFu; rowMaxU[i] = 0u;

  // ---- per-sample losses ----
  float l0=logits[3*i], l1=logits[3*i+1], l2=logits[3*i+2];
  int t = targets[i];
  float m = fmaxf(l0, fmaxf(l1,l2));
  float e0=expf(l0-m), e1=expf(l1-m), e2=expf(l2-m);
  float se = e0+e1+e2;
  float lse = m + logf(se);
  float lp0=l0-lse, lp1=l1-lse, lp2=l2-lse;
  float lpt = (t==0)?lp0:((t==1)?lp1:lp2);
  float nll = -lpt;
  float ce_ls = 0.9f*nll + 0.1f*(-(lp0+lp1+lp2)*(1.f/3.f));
  float pt = expf(-ce_ls);
  float om = 1.f - pt;
  float focal_i = fa[t]*om*om*ce_ls;
  float w = cw[t];
  float ce_n = w*nll, ce_d = w;
  float p0=e0/se, p1=e1/se, p2=e2/se;
  float bnd;
  if (t==0)      bnd = p1 + 0.6f*p2;
  else if (t==2) bnd = p1 + 0.4f*p0;
  else           bnd = 4.5f*(1.f - p1 + 0.3f*(p0+p2));
  float a0=alpha[3*i], a1=alpha[3*i+1], a2=alpha[3*i+2];
  float S = a0+a1+a2 + 1e-8f;
  float at_ = (t==0)?a0:((t==1)?a1:a2);
  float lik = digammaf_(S) - digammaf_(at_ + 1e-8f);
  float b0 = (t==0)?1.f:a0, b1 = (t==1)?1.f:a1, b2 = (t==2)?1.f:a2;
  float ats = b0+b1+b2 + 1e-8f;
  float psa = digammaf_(ats + 1e-8f);
  float kl = lgammaf(ats)
     - (lgammaf(b0+1e-8f)+lgammaf(b1+1e-8f)+lgammaf(b2+1e-8f))
     + (b0-1.f)*(digammaf_(b0+1e-8f)-psa)
     + (b1-1.f)*(digammaf_(b1+1e-8f)-psa)
     + (b2-1.f)*(digammaf_(b2+1e-8f)-psa);

  unsigned long long m0 = __ballot(t==0);
  unsigned long long m1 = __ballot(t==1);
  unsigned long long m2 = __ballot(t==2);
  #pragma unroll
  for (int off=32; off; off>>=1){
    focal_i += __shfl_xor(focal_i, off);
    ce_n    += __shfl_xor(ce_n, off);
    ce_d    += __shfl_xor(ce_d, off);
    bnd     += __shfl_xor(bnd, off);
    lik     += __shfl_xor(lik, off);
    kl      += __shfl_xor(kl, off);
  }
  if (lane == 0){
    int slot = bid*4 + wave;
    psum[slot*8+0]=focal_i; psum[slot*8+1]=ce_n; psum[slot*8+2]=ce_d;
    psum[slot*8+3]=bnd;     psum[slot*8+4]=lik;  psum[slot*8+5]=kl;
    pcnt[slot*4+0]=(unsigned)__popcll(m0);
    pcnt[slot*4+1]=(unsigned)__popcll(m1);
    pcnt[slot*4+2]=(unsigned)__popcll(m2);
  }
}

// ============ k_pairs: SINGLE-WAVE blocks, 64x64 tile, NO barriers ==========
// 2080 blocks x 64 threads, triangular (by<=bx). One wave owns the whole tile
// (4x4 of 16x16x32 MFMA), double-buffered private LDS, global_load_lds w16.
// No __syncthreads anywhere -> compiler emits fine-grained per-wave
// s_waitcnt vmcnt(N)/lgkmcnt(N) only (AITER-style pipeline, no barrier drain).
__global__ __launch_bounds__(64, 3) void k_pairs(const __bf16* __restrict__ fb,
    const int* __restrict__ targets, int B, int D,
    float* __restrict__ pairPart, unsigned* rowMinU, unsigned* rowMaxU){
  __shared__ __bf16 sA[2][2048];   // [buf][64 rows x 32 k]
  __shared__ __bf16 sB[2][2048];

  // decode triangular tile index -> (by, bx), by <= bx
  int t = blockIdx.x;
  int bx = (int)((sqrtf(8.f*(float)t + 1.f) - 1.f)*0.5f);
  while ((bx+1)*(bx+2)/2 <= t) bx++;
  while (bx*(bx+1)/2 > t) bx--;
  int by = t - bx*(bx+1)/2;
  bool isDiag = (by == bx);
  int rowBase = by*64, colBase = bx*64;

  int lane = threadIdx.x;
  int quad = lane >> 4, l16 = lane & 15;

  // per-lane global staging pointers: inst j stages rows [j*16, j*16+16),
  // lane -> (row = j*16 + lane/4, cb = lane&3), global cb swizzled.
  const __bf16* gA[4]; const __bf16* gB[4];
  #pragma unroll
  for (int j=0; j<4; j++){
    int row = j*16 + (lane >> 2);
    int gcb = (lane & 3) ^ ((row >> 1) & 3);
    gA[j] = fb + (size_t)(rowBase + row)*D + gcb*8;
    gB[j] = fb + (size_t)(colBase + row)*D + gcb*8;
  }

  // fragment LDS offsets (elements), inverse swizzle
  int offA[4], offB[4];
  #pragma unroll
  for (int mi=0; mi<4; mi++){
    int R = mi*16 + l16;
    offA[mi] = R*32 + ((quad ^ ((R>>1)&3))*8);
    offB[mi] = offA[mi];
  }

  f32x4 C[4][4] = {};

#if USE_GLL
  #define STAGE(buf, k0) do{ \
    gll16(gA[0] + (k0), &sA[buf][0*512]); \
    gll16(gA[1] + (k0), &sA[buf][1*512]); \
    gll16(gA[2] + (k0), &sA[buf][2*512]); \
    gll16(gA[3] + (k0), &sA[buf][3*512]); \
    gll16(gB[0] + (k0), &sB[buf][0*512]); \
    gll16(gB[1] + (k0), &sB[buf][1*512]); \
    gll16(gB[2] + (k0), &sB[buf][2*512]); \
    gll16(gB[3] + (k0), &sB[buf][3*512]); \
  }while(0)
#else
  #define STAGE(buf, k0) do{ \
    _Pragma("unroll") \
    for (int j=0; j<4; j++){ \
      *(bf8*)&sA[buf][j*512 + lane*8] = *(const bf8*)(gA[j] + (k0)); \
      *(bf8*)&sB[buf][j*512 + lane*8] = *(const bf8*)(gB[j] + (k0)); \
    } \
  }while(0)
#endif

  #define COMPUTE(buf) do{ \
    bf8 aF[4], bF[4]; \
    _Pragma("unroll") \
    for (int mi=0; mi<4; mi++) aF[mi] = *(const bf8*)(&sA[buf][offA[mi]]); \
    _Pragma("unroll") \
    for (int ni=0; ni<4; ni++) bF[ni] = *(const bf8*)(&sB[buf][offB[ni]]); \
    _Pragma("unroll") \
    for (int mi=0; mi<4; mi++) \
      _Pragma("unroll") \
      for (int ni=0; ni<4; ni++) \
        C[mi][ni] = __builtin_amdgcn_mfma_f32_16x16x32_bf16(aF[mi], bF[ni], C[mi][ni], 0,0,0); \
  }while(0)

  int NIT = D/32;   // 16 (even)
  STAGE(0, 0);
  for (int it=0; it<NIT; it+=2){
    STAGE(1, (it+1)*32);
    COMPUTE(0);
    if (it+2 < NIT) STAGE(0, (it+2)*32);
    COMPUTE(1);
  }

  // ---- fused epilogue (single wave; no LDS needed for reductions) ----
  int tcol[4];
  #pragma unroll
  for (int ni=0; ni<4; ni++) tcol[ni] = targets[colBase + ni*16 + l16];

  float pos=0.f, neg=0.f, semi=0.f, diag=0.f;
  float cmin[4], cmax[4];
  #pragma unroll
  for (int ni=0; ni<4; ni++){ cmin[ni]=2.f; cmax[ni]=-2.f; }

  #pragma unroll
  for (int mi=0; mi<4; mi++){
    #pragma unroll
    for (int r=0; r<4; r++){
      int rl = mi*16 + quad*4 + r;
      int row = rowBase + rl;
      int tr = targets[row];
      float vmin = 2.f, vmax = -2.f;
      #pragma unroll
      for (int ni=0; ni<4; ni++){
        int col = colBase + ni*16 + l16;
        float s = C[mi][ni][r];
        if (tr == tcol[ni]){
          float omv = 1.f - s;
          float q = omv*omv;
          pos += q;
          if (tr == 1) semi += q;
          if (row == col) diag += q;     // only possible on diagonal tiles
          else {
            vmin = fminf(vmin, s);
            cmin[ni] = fminf(cmin[ni], s);
          }
        } else {
          float c0 = fmaxf(s - 0.2f, 0.f);
          neg += c0*c0;
          vmax = fmaxf(vmax, s);
          cmax[ni] = fmaxf(cmax[ni], s);
        }
      }
      // reduce across the 16 lanes of this quad (they share `row`)
      #pragma unroll
      for (int off=1; off<16; off<<=1){
        vmin = fminf(vmin, __shfl_xor(vmin, off));
        vmax = fmaxf(vmax, __shfl_xor(vmax, off));
      }
      if (l16 == 0){
        atomicMin(&rowMinU[row], mapf(vmin));
        atomicMax(&rowMaxU[row], mapf(vmax));
      }
    }
  }

  // column-direction (transpose) contribution for off-diagonal tiles
  if (!isDiag){
    #pragma unroll
    for (int ni=0; ni<4; ni++){
      float cn = cmin[ni], cx = cmax[ni];
      cn = fminf(cn, __shfl_xor(cn, 16)); cn = fminf(cn, __shfl_xor(cn, 32));
      cx = fmaxf(cx, __shfl_xor(cx, 16)); cx = fmaxf(cx, __shfl_xor(cx, 32));
      if (quad == 0){
        int col = colBase + ni*16 + l16;
        atomicMin(&rowMinU[col], mapf(cn));
        atomicMax(&rowMaxU[col], mapf(cx));
      }
    }
  }

  #pragma unroll
  for (int off=32; off; off>>=1){
    pos  += __shfl_xor(pos, off);
    neg  += __shfl_xor(neg, off);
    semi += __shfl_xor(semi, off);
    diag += __shfl_xor(diag, off);
  }
  if (lane == 0){
    float fac = isDiag ? 1.f : 2.f;
    pairPart[blockIdx.x*4+0] = pos*fac;
    pairPart[blockIdx.x*4+1] = neg*fac;
    pairPart[blockIdx.x*4+2] = semi*fac;
    pairPart[blockIdx.x*4+3] = diag;
  }
}

// ============ k_final: reduce slots + triplet + combine ============
__global__ __launch_bounds__(256) void k_final(const int* __restrict__ targets,
    const int* __restrict__ epoch_p, int B, int SB, int nblk,
    const float* __restrict__ pairPart, const float* __restrict__ psum,
    const unsigned* __restrict__ pcnt,
    const unsigned* rowMinU, const unsigned* rowMaxU, float* out){
  __shared__ float tot[6];
  __shared__ unsigned cn[3];
  __shared__ float ptot[4];
  int tid = threadIdx.x;
  int nslots = SB*4;
  int wave = tid>>6, lane = tid&63;

  // reduce per-sample partials (wave 0)
  if (tid < 64){
    float v0=0,v1=0,v2=0,v3=0,v4=0,v5=0;
    int c0=0,c1=0,c2=0;
    for (int s=tid; s<nslots; s+=64){
      v0+=psum[s*8+0]; v1+=psum[s*8+1]; v2+=psum[s*8+2];
      v3+=psum[s*8+3]; v4+=psum[s*8+4]; v5+=psum[s*8+5];
      c0+=(int)pcnt[s*4+0]; c1+=(int)pcnt[s*4+1]; c2+=(int)pcnt[s*4+2];
    }
    #pragma unroll
    for (int off=32; off; off>>=1){
      v0+=__shfl_xor(v0,off); v1+=__shfl_xor(v1,off); v2+=__shfl_xor(v2,off);
      v3+=__shfl_xor(v3,off); v4+=__shfl_xor(v4,off); v5+=__shfl_xor(v5,off);
      c0+=__shfl_xor(c0,off); c1+=__shfl_xor(c1,off); c2+=__shfl_xor(c2,off);
    }
    if (tid == 0){
      tot[0]=v0; tot[1]=v1; tot[2]=v2; tot[3]=v3; tot[4]=v4; tot[5]=v5;
      cn[0]=(unsigned)c0; cn[1]=(unsigned)c1; cn[2]=(unsigned)c2;
    }
  }

  // reduce pair partials (all 256 threads)
  {
    float p=0,n=0,s2=0,d=0;
    for (int s=tid; s<nblk; s+=256){
      p += pairPart[s*4+0]; n += pairPart[s*4+1];
      s2+= pairPart[s*4+2]; d += pairPart[s*4+3];
    }
    #pragma unroll
    for (int off=32; off; off>>=1){
      p+=__shfl_xor(p,off); n+=__shfl_xor(n,off);
      s2+=__shfl_xor(s2,off); d+=__shfl_xor(d,off);
    }
    __shared__ float pw[4][4];
    if (lane==0){ pw[wave][0]=p; pw[wave][1]=n; pw[wave][2]=s2; pw[wave][3]=d; }
    __syncthreads();
    if (tid==0){
      float a=0,b=0,c=0,e=0;
      for (int w2=0; w2<4; w2++){ a+=pw[w2][0]; b+=pw[w2][1]; c+=pw[w2][2]; e+=pw[w2][3]; }
      ptot[0]=a; ptot[1]=b; ptot[2]=c; ptot[3]=e;
    }
  }
  __syncthreads();
  int n0=(int)cn[0], n1=(int)cn[1], n2=(int)cn[2];

  float tsum = 0.f, tcnt = 0.f;
  for (int i = tid; i < B; i += 256){
    int t = targets[i];
    int nt = (t==0)?n0:((t==1)?n1:n2);
    if (nt - 1 > 0 && B - nt > 0){
      float mn = unmapf(rowMinU[i]);
      float mx = unmapf(rowMaxU[i]);
      float hp = sqrtf(fmaxf(2.f - 2.f*mn, 0.f));
      float hn = sqrtf(fmaxf(2.f - 2.f*mx, 0.f));
      float margin = 1.5f * ((t==1) ? 2.5f : 1.f);
      float tl = fmaxf(hp - hn + margin, 0.f);
      tsum += tl; tcnt += 1.f;
    }
  }
  #pragma unroll
  for (int off=32; off; off>>=1){ tsum += __shfl_xor(tsum, off); tcnt += __shfl_xor(tcnt, off); }
  __shared__ float sb[4][2];
  if (lane==0){ sb[wave][0]=tsum; sb[wave][1]=tcnt; }
  __syncthreads();
  if (tid==0){
    float ts=0, tn=0;
    for (int w2=0;w2<4;w2++){ ts+=sb[w2][0]; tn+=sb[w2][1]; }
    float triplet = (tn > 0.f) ? ts / fmaxf(tn, 1.f) : 0.f;
    float pos=ptot[0], neg=ptot[1], semi=ptot[2], diag=ptot[3];
    float Bf = (float)B;
    float focal = tot[0] / Bf;
    float ce = tot[1] / tot[2];
    float boundary = tot[3] / (Bf + 1e-8f);
    float contrastive = (pos + neg + 4.f*semi) / (Bf*Bf + 1e-8f);
    long long npl = ((long long)n0*(n0-1) + (long long)n1*(n1-1) + (long long)n2*(n2-1))/2;
    float qsum = (pos - diag) * 0.5f;
    float q = qsum / (float)(npl > 0 ? npl : 1);
    if (n2 > 0) q *= (1.f + 2.5f * ((float)n2 / Bf));
    float quality = (npl > 0) ? q : 0.f;
    int ep = epoch_p[0];
    float er = (float)ep / 25.f;
    float ann = fminf(1.f, er*er);
    float evidential = tot[4]/Bf + ann*0.2f*tot[5]/Bf;
    float total = 0.4f*focal + 0.3f*ce + 0.15f*boundary
                + 0.1f*contrastive + 0.1f*triplet + 0.1f*quality + 0.1f*evidential;
    out[0] = total;
  }
}

extern "C" void kernel_launch(void* const* d_in, const int* in_sizes, int n_in,
                              void* d_out, int out_size, void* d_ws, size_t ws_size,
                              hipStream_t stream){
  const float* logits   = (const float*)d_in[0];
  const int*   targets  = (const int*)d_in[1];
  const float* features = (const float*)d_in[2];
  const float* alpha    = (const float*)d_in[3];
  const int*   epoch    = (const int*)d_in[4];
  const float* fa       = (const float*)d_in[5];
  const float* cw       = (const float*)d_in[6];
  int B = in_sizes[1];
  int D = in_sizes[2] / B;
  int SB = B >> 8;
  int T  = B / 64;
  int nblk = T*(T+1)/2;            // triangular: by <= bx

  char* ws = (char*)d_ws;
  unsigned* pcnt     = (unsigned*)(ws);                       // SB*4*4 u32
  float*    psum     = (float*)(ws + 16384);                  // SB*4*8 f32
  float*    pairPart = (float*)(ws + 32768);                  // nblk*4 f32 (~33KB)
  unsigned* rowMinU  = (unsigned*)(ws + 131072);
  unsigned* rowMaxU  = (unsigned*)(ws + 131072 + (size_t)B*4);
  __bf16*   fb       = (__bf16*)(ws + 131072 + (size_t)B*8);

  k_prep <<<B/4, 256, 0, stream>>>(features, fb, logits, targets, alpha, fa, cw,
                                   B, D, psum, pcnt, rowMinU, rowMaxU);
  k_pairs<<<nblk, 64, 0, stream>>>(fb, targets, B, D, pairPart, rowMinU, rowMaxU);
  k_final<<<1, 256, 0, stream>>>(targets, epoch, B, SB, nblk, pairPart, psum, pcnt,
                                 rowMinU, rowMaxU, (float*)d_out);
}

// Round 7
// 120.028 us; speedup vs baseline: 1.6918x; 1.0646x over previous
//
#include <hip/hip_runtime.h>
#include <hip/hip_bf16.h>
#include <cstdint>

typedef __attribute__((ext_vector_type(8))) __bf16 bf8;
typedef __attribute__((ext_vector_type(4))) float f32x4;

#if defined(__has_builtin)
#if __has_builtin(__builtin_amdgcn_global_load_lds)
#define USE_GLL 1
#endif
#endif
#ifndef USE_GLL
#define USE_GLL 0
#endif

#if USE_GLL
// NOTE: global src is a PER-LANE address; LDS dst is wave-uniform base,
// HW deposits lane i at dst + i*16B. (Round-6 bug: uniform src broadcast.)
__device__ __forceinline__ void gll16(const __bf16* g, __bf16* l){
  __builtin_amdgcn_global_load_lds(
      (const __attribute__((address_space(1))) void*)g,
      (__attribute__((address_space(3))) void*)l, 16, 0, 0);
}
#endif

// order-preserving float<->uint maps (for atomicMin/Max on sim values)
__device__ __forceinline__ unsigned mapf(float x){
  unsigned u = __float_as_uint(x);
  return (u & 0x80000000u) ? ~u : (u | 0x80000000u);
}
__device__ __forceinline__ float unmapf(unsigned u){
  return __uint_as_float((u & 0x80000000u) ? (u & 0x7FFFFFFFu) : ~u);
}

__device__ float digammaf_(float x){
  float r = 0.f;
  while (x < 6.f){ r -= 1.f/x; x += 1.f; }
  float inv = 1.f/x, inv2 = inv*inv;
  r += logf(x) - 0.5f*inv
     - inv2*(0.08333333333f - inv2*(0.008333333333f - inv2*0.003968253968f));
  return r;
}

// ============ k_prep: normalize -> TILED bf16 (fb2) + per-sample losses =====
// fb2 layout: panel p=row/64 (64 rows), chunk c=k/32; each chunk is 4KB
// CONTIGUOUS: elem (r=row%64, kk=k%32) at (p*16+c)*2048 + r*32 + cb'*8 + kk%8,
// cb' = (kk/8) ^ ((r>>1)&3)  (bank swizzle pre-baked into the layout).
__global__ __launch_bounds__(256) void k_prep(const float* __restrict__ feat,
    __bf16* __restrict__ fb2,
    const float* __restrict__ logits, const int* __restrict__ targets,
    const float* __restrict__ alpha,  const float* __restrict__ fa,
    const float* __restrict__ cw, int B, int D,
    float* __restrict__ psum, unsigned* rowMinU, unsigned* rowMaxU){
  int bid = blockIdx.x, tid = threadIdx.x;
  int wave = tid >> 6, lane = tid & 63;
  __shared__ float sloc[4][8];

  int row = bid*4 + wave;                       // grid = B/4, always < B
  // ---- normalize one row per wave ----
  const float* src = feat + (size_t)row*D;
  float ss = 0.f;
  for (int c = lane*4; c < D; c += 64*4){
    float4 v = *(const float4*)(src + c);
    ss += v.x*v.x + v.y*v.y + v.z*v.z + v.w*v.w;
  }
  #pragma unroll
  for (int off=32; off; off>>=1) ss += __shfl_xor(ss, off);
  float inv = 1.f / fmaxf(sqrtf(ss), 1e-12f);

  int p = row >> 6, r = row & 63;
  int rsw = (r >> 1) & 3;
  for (int c = lane*8; c < D; c += 64*8){
    float4 v0 = *(const float4*)(src + c);
    float4 v1 = *(const float4*)(src + c + 4);
    bf8 o;
    o[0]=(__bf16)(v0.x*inv); o[1]=(__bf16)(v0.y*inv);
    o[2]=(__bf16)(v0.z*inv); o[3]=(__bf16)(v0.w*inv);
    o[4]=(__bf16)(v1.x*inv); o[5]=(__bf16)(v1.y*inv);
    o[6]=(__bf16)(v1.z*inv); o[7]=(__bf16)(v1.w*inv);
    int cc = c >> 5;                  // chunk
    int cb = (c >> 3) & 3;            // 8-elem group within chunk
    size_t off = (size_t)(p*16 + cc)*2048 + r*32 + ((cb ^ rsw)*8);
    *(bf8*)(fb2 + off) = o;
  }

  // ---- init row min/max (4 rows per block) ----
  if (tid < 4){ rowMinU[bid*4+tid] = 0xFFFFFFFFu; rowMaxU[bid*4+tid] = 0u; }

  // ---- per-sample losses: sample i = row (redundant across lanes) ----
  int i = row;
  float l0=logits[3*i], l1=logits[3*i+1], l2=logits[3*i+2];
  int t = targets[i];
  float m = fmaxf(l0, fmaxf(l1,l2));
  float e0=expf(l0-m), e1=expf(l1-m), e2=expf(l2-m);
  float se = e0+e1+e2;
  float lse = m + logf(se);
  float lp0=l0-lse, lp1=l1-lse, lp2=l2-lse;
  float lpt = (t==0)?lp0:((t==1)?lp1:lp2);
  float nll = -lpt;
  float ce_ls = 0.9f*nll + 0.1f*(-(lp0+lp1+lp2)*(1.f/3.f));
  float pt = expf(-ce_ls);
  float om = 1.f - pt;
  float focal_i = fa[t]*om*om*ce_ls;
  float w = cw[t];
  float ce_n = w*nll, ce_d = w;
  float p0=e0/se, p1=e1/se, p2=e2/se;
  float bnd;
  if (t==0)      bnd = p1 + 0.6f*p2;
  else if (t==2) bnd = p1 + 0.4f*p0;
  else           bnd = 4.5f*(1.f - p1 + 0.3f*(p0+p2));
  float a0=alpha[3*i], a1=alpha[3*i+1], a2=alpha[3*i+2];
  float S = a0+a1+a2 + 1e-8f;
  float at_ = (t==0)?a0:((t==1)?a1:a2);
  float lik = digammaf_(S) - digammaf_(at_ + 1e-8f);
  float b0 = (t==0)?1.f:a0, b1 = (t==1)?1.f:a1, b2 = (t==2)?1.f:a2;
  float ats = b0+b1+b2 + 1e-8f;
  float psa = digammaf_(ats + 1e-8f);
  float kl = lgammaf(ats)
     - (lgammaf(b0+1e-8f)+lgammaf(b1+1e-8f)+lgammaf(b2+1e-8f))
     + (b0-1.f)*(digammaf_(b0+1e-8f)-psa)
     + (b1-1.f)*(digammaf_(b1+1e-8f)-psa)
     + (b2-1.f)*(digammaf_(b2+1e-8f)-psa);
  if (lane == 0){
    sloc[wave][0]=focal_i; sloc[wave][1]=ce_n; sloc[wave][2]=ce_d;
    sloc[wave][3]=bnd;     sloc[wave][4]=lik;  sloc[wave][5]=kl;
  }
  __syncthreads();
  if (tid < 6)
    psum[bid*8+tid] = sloc[0][tid]+sloc[1][tid]+sloc[2][tid]+sloc[3][tid];
}

// ============ k_pairs: single-wave 64x64 tiles over TILED fb2 ==============
// 2080 blocks x 64 threads, triangular (by<=bx), no barriers. Staging reads
// 4KB contiguous chunks (4 x gll16, each lane 16B -> 1KB sequential per inst,
// 8 full cache lines, zero scatter). LDS chunk layout == fb2 chunk layout.
// Diagonal blocks stage A only and read B-fragments from sA.
__global__ __launch_bounds__(64) void k_pairs(const __bf16* __restrict__ fb2,
    const int* __restrict__ targets, int B, int D,
    float* __restrict__ pairPart, unsigned* rowMinU, unsigned* rowMaxU){
  __shared__ __bf16 sA[2][2048];
  __shared__ __bf16 sB[2][2048];

  // decode triangular tile index -> (by, bx), by <= bx
  int t = blockIdx.x;
  int bx = (int)((sqrtf(8.f*(float)t + 1.f) - 1.f)*0.5f);
  while ((bx+1)*(bx+2)/2 <= t) bx++;
  while (bx*(bx+1)/2 > t) bx--;
  int by = t - bx*(bx+1)/2;
  bool isDiag = (by == bx);
  int rowBase = by*64, colBase = bx*64;

  int lane = threadIdx.x;
  int quad = lane >> 4, l16 = lane & 15;
  int NCH = D/32;                                   // 16 chunks per panel

  const __bf16* srcA = fb2 + (size_t)by*NCH*2048 + lane*8;  // per-lane 16B
  const __bf16* srcB = fb2 + (size_t)bx*NCH*2048 + lane*8;
  const __bf16* sB0  = isDiag ? &sA[0][0] : &sB[0][0];

  // fragment LDS offsets (elements), inverse swizzle; A and B identical form
  int offA[4];
  #pragma unroll
  for (int mi=0; mi<4; mi++){
    int R = mi*16 + l16;
    offA[mi] = R*32 + ((quad ^ ((R>>1)&3))*8);
  }

  f32x4 C[4][4] = {};

#if USE_GLL
  #define STAGE(buf, it) do{ \
    const __bf16* ga_ = srcA + (it)*2048; \
    gll16(ga_ + 0*512, &sA[buf][0*512]); \
    gll16(ga_ + 1*512, &sA[buf][1*512]); \
    gll16(ga_ + 2*512, &sA[buf][2*512]); \
    gll16(ga_ + 3*512, &sA[buf][3*512]); \
    if (!isDiag){ \
      const __bf16* gb_ = srcB + (it)*2048; \
      gll16(gb_ + 0*512, &sB[buf][0*512]); \
      gll16(gb_ + 1*512, &sB[buf][1*512]); \
      gll16(gb_ + 2*512, &sB[buf][2*512]); \
      gll16(gb_ + 3*512, &sB[buf][3*512]); \
    } \
  }while(0)
#else
  #define STAGE(buf, it) do{ \
    const __bf16* ga_ = srcA + (it)*2048; \
    _Pragma("unroll") \
    for (int j=0; j<4; j++) \
      *(bf8*)&sA[buf][j*512 + lane*8] = *(const bf8*)(ga_ + j*512); \
    if (!isDiag){ \
      const __bf16* gb_ = srcB + (it)*2048; \
      _Pragma("unroll") \
      for (int j=0; j<4; j++) \
        *(bf8*)&sB[buf][j*512 + lane*8] = *(const bf8*)(gb_ + j*512); \
    } \
  }while(0)
#endif

  #define COMPUTE(buf) do{ \
    bf8 aF[4], bF[4]; \
    _Pragma("unroll") \
    for (int mi=0; mi<4; mi++) aF[mi] = *(const bf8*)(&sA[0][0] + (buf)*2048 + offA[mi]); \
    _Pragma("unroll") \
    for (int ni=0; ni<4; ni++) bF[ni] = *(const bf8*)(sB0 + (buf)*2048 + offA[ni]); \
    _Pragma("unroll") \
    for (int mi=0; mi<4; mi++) \
      _Pragma("unroll") \
      for (int ni=0; ni<4; ni++) \
        C[mi][ni] = __builtin_amdgcn_mfma_f32_16x16x32_bf16(aF[mi], bF[ni], C[mi][ni], 0,0,0); \
  }while(0)

  STAGE(0, 0);
  for (int it=0; it<NCH; it+=2){
    STAGE(1, it+1);
    COMPUTE(0);
    if (it+2 < NCH) STAGE(0, it+2);
    COMPUTE(1);
  }

  // ---- fused epilogue (validated rounds 1-5, absmax 0) ----
  int tcol[4];
  #pragma unroll
  for (int ni=0; ni<4; ni++) tcol[ni] = targets[colBase + ni*16 + l16];

  float pos=0.f, neg=0.f, semi=0.f, diag=0.f;
  float cmin[4], cmax[4];
  #pragma unroll
  for (int ni=0; ni<4; ni++){ cmin[ni]=2.f; cmax[ni]=-2.f; }

  #pragma unroll
  for (int mi=0; mi<4; mi++){
    #pragma unroll
    for (int r=0; r<4; r++){
      int rl = mi*16 + quad*4 + r;
      int row = rowBase + rl;
      int tr = targets[row];
      float vmin = 2.f, vmax = -2.f;
      #pragma unroll
      for (int ni=0; ni<4; ni++){
        int col = colBase + ni*16 + l16;
        float s = C[mi][ni][r];
        if (tr == tcol[ni]){
          float omv = 1.f - s;
          float q = omv*omv;
          pos += q;
          if (tr == 1) semi += q;
          if (row == col) diag += q;     // only possible on diagonal tiles
          else {
            vmin = fminf(vmin, s);
            cmin[ni] = fminf(cmin[ni], s);
          }
        } else {
          float c0 = fmaxf(s - 0.2f, 0.f);
          neg += c0*c0;
          vmax = fmaxf(vmax, s);
          cmax[ni] = fmaxf(cmax[ni], s);
        }
      }
      #pragma unroll
      for (int off=1; off<16; off<<=1){
        vmin = fminf(vmin, __shfl_xor(vmin, off));
        vmax = fmaxf(vmax, __shfl_xor(vmax, off));
      }
      if (l16 == 0){
        atomicMin(&rowMinU[row], mapf(vmin));
        atomicMax(&rowMaxU[row], mapf(vmax));
      }
    }
  }

  if (!isDiag){
    #pragma unroll
    for (int ni=0; ni<4; ni++){
      float cn = cmin[ni], cx = cmax[ni];
      cn = fminf(cn, __shfl_xor(cn, 16)); cn = fminf(cn, __shfl_xor(cn, 32));
      cx = fmaxf(cx, __shfl_xor(cx, 16)); cx = fmaxf(cx, __shfl_xor(cx, 32));
      if (quad == 0){
        int col = colBase + ni*16 + l16;
        atomicMin(&rowMinU[col], mapf(cn));
        atomicMax(&rowMaxU[col], mapf(cx));
      }
    }
  }

  #pragma unroll
  for (int off=32; off; off>>=1){
    pos  += __shfl_xor(pos, off);
    neg  += __shfl_xor(neg, off);
    semi += __shfl_xor(semi, off);
    diag += __shfl_xor(diag, off);
  }
  if (lane == 0){
    float fac = isDiag ? 1.f : 2.f;
    pairPart[blockIdx.x*4+0] = pos*fac;
    pairPart[blockIdx.x*4+1] = neg*fac;
    pairPart[blockIdx.x*4+2] = semi*fac;
    pairPart[blockIdx.x*4+3] = diag;
  }
}

// ============ k_final: 1024 threads; histogram + reductions + combine ======
__global__ __launch_bounds__(1024) void k_final(const int* __restrict__ targets,
    const int* __restrict__ epoch_p, int B, int nprep, int nblk,
    const float* __restrict__ pairPart, const float* __restrict__ psum,
    const unsigned* rowMinU, const unsigned* rowMaxU, float* out){
  int tid = threadIdx.x, wave = tid>>6, lane = tid&63;
  __shared__ float redf[16][8];
  __shared__ int   redi[16][4];
  __shared__ float tot6[6];
  __shared__ int   cns[3];
  __shared__ float ptot[4];

  // ---- 1) histogram targets (int4 loads) ----
  {
    int c0=0,c1=0,c2=0;
    for (int i4 = tid; i4 < B/4; i4 += 1024){
      int4 tv = ((const int4*)targets)[i4];
      c0 += (tv.x==0)+(tv.y==0)+(tv.z==0)+(tv.w==0);
      c1 += (tv.x==1)+(tv.y==1)+(tv.z==1)+(tv.w==1);
      c2 += (tv.x==2)+(tv.y==2)+(tv.z==2)+(tv.w==2);
    }
    #pragma unroll
    for (int off=32; off; off>>=1){
      c0+=__shfl_xor(c0,off); c1+=__shfl_xor(c1,off); c2+=__shfl_xor(c2,off);
    }
    if (lane==0){ redi[wave][0]=c0; redi[wave][1]=c1; redi[wave][2]=c2; }
  }
  // ---- 2) per-sample partials ----
  {
    float v0=0,v1=0,v2=0,v3=0,v4=0,v5=0;
    for (int s = tid; s < nprep; s += 1024){
      float4 a = *(const float4*)(psum + s*8);
      float4 b = *(const float4*)(psum + s*8 + 4);
      v0+=a.x; v1+=a.y; v2+=a.z; v3+=a.w; v4+=b.x; v5+=b.y;
    }
    #pragma unroll
    for (int off=32; off; off>>=1){
      v0+=__shfl_xor(v0,off); v1+=__shfl_xor(v1,off); v2+=__shfl_xor(v2,off);
      v3+=__shfl_xor(v3,off); v4+=__shfl_xor(v4,off); v5+=__shfl_xor(v5,off);
    }
    if (lane==0){
      redf[wave][0]=v0; redf[wave][1]=v1; redf[wave][2]=v2;
      redf[wave][3]=v3; redf[wave][4]=v4; redf[wave][5]=v5;
    }
  }
  __syncthreads();
  if (tid == 0){
    int c0=0,c1=0,c2=0;
    float v[6]={0,0,0,0,0,0};
    for (int w2=0; w2<16; w2++){
      c0+=redi[w2][0]; c1+=redi[w2][1]; c2+=redi[w2][2];
      for (int j=0;j<6;j++) v[j]+=redf[w2][j];
    }
    cns[0]=c0; cns[1]=c1; cns[2]=c2;
    for (int j=0;j<6;j++) tot6[j]=v[j];
  }
  __syncthreads();

  // ---- 3) pair partials ----
  {
    float p=0,n=0,s2=0,d=0;
    for (int s = tid; s < nblk; s += 1024){
      float4 a = *(const float4*)(pairPart + s*4);
      p+=a.x; n+=a.y; s2+=a.z; d+=a.w;
    }
    #pragma unroll
    for (int off=32; off; off>>=1){
      p+=__shfl_xor(p,off); n+=__shfl_xor(n,off);
      s2+=__shfl_xor(s2,off); d+=__shfl_xor(d,off);
    }
    if (lane==0){ redf[wave][0]=p; redf[wave][1]=n; redf[wave][2]=s2; redf[wave][3]=d; }
  }
  __syncthreads();
  if (tid == 0){
    float a=0,b=0,c=0,e=0;
    for (int w2=0; w2<16; w2++){ a+=redf[w2][0]; b+=redf[w2][1]; c+=redf[w2][2]; e+=redf[w2][3]; }
    ptot[0]=a; ptot[1]=b; ptot[2]=c; ptot[3]=e;
  }
  __syncthreads();

  int n0=cns[0], n1=cns[1], n2=cns[2];

  // ---- 4) triplet ----
  float tsum = 0.f, tcnt = 0.f;
  for (int i = tid; i < B; i += 1024){
    int t = targets[i];
    int nt = (t==0)?n0:((t==1)?n1:n2);
    if (nt - 1 > 0 && B - nt > 0){
      float mn = unmapf(rowMinU[i]);
      float mx = unmapf(rowMaxU[i]);
      float hp = sqrtf(fmaxf(2.f - 2.f*mn, 0.f));
      float hn = sqrtf(fmaxf(2.f - 2.f*mx, 0.f));
      float margin = 1.5f * ((t==1) ? 2.5f : 1.f);
      float tl = fmaxf(hp - hn + margin, 0.f);
      tsum += tl; tcnt += 1.f;
    }
  }
  #pragma unroll
  for (int off=32; off; off>>=1){ tsum += __shfl_xor(tsum, off); tcnt += __shfl_xor(tcnt, off); }
  if (lane==0){ redf[wave][6]=tsum; redf[wave][7]=tcnt; }
  __syncthreads();

  if (tid==0){
    float ts=0, tn=0;
    for (int w2=0; w2<16; w2++){ ts+=redf[w2][6]; tn+=redf[w2][7]; }
    float triplet = (tn > 0.f) ? ts / fmaxf(tn, 1.f) : 0.f;
    float pos=ptot[0], neg=ptot[1], semi=ptot[2], diag=ptot[3];
    float Bf = (float)B;
    float focal = tot6[0] / Bf;
    float ce = tot6[1] / tot6[2];
    float boundary = tot6[3] / (Bf + 1e-8f);
    float contrastive = (pos + neg + 4.f*semi) / (Bf*Bf + 1e-8f);
    long long npl = ((long long)n0*(n0-1) + (long long)n1*(n1-1) + (long long)n2*(n2-1))/2;
    float qsum = (pos - diag) * 0.5f;
    float q = qsum / (float)(npl > 0 ? npl : 1);
    if (n2 > 0) q *= (1.f + 2.5f * ((float)n2 / Bf));
    float quality = (npl > 0) ? q : 0.f;
    int ep = epoch_p[0];
    float er = (float)ep / 25.f;
    float ann = fminf(1.f, er*er);
    float evidential = tot6[4]/Bf + ann*0.2f*tot6[5]/Bf;
    float total = 0.4f*focal + 0.3f*ce + 0.15f*boundary
                + 0.1f*contrastive + 0.1f*triplet + 0.1f*quality + 0.1f*evidential;
    out[0] = total;
  }
}

extern "C" void kernel_launch(void* const* d_in, const int* in_sizes, int n_in,
                              void* d_out, int out_size, void* d_ws, size_t ws_size,
                              hipStream_t stream){
  const float* logits   = (const float*)d_in[0];
  const int*   targets  = (const int*)d_in[1];
  const float* features = (const float*)d_in[2];
  const float* alpha    = (const float*)d_in[3];
  const int*   epoch    = (const int*)d_in[4];
  const float* fa       = (const float*)d_in[5];
  const float* cw       = (const float*)d_in[6];
  int B = in_sizes[1];
  int D = in_sizes[2] / B;
  int nprep = B/4;                 // k_prep blocks == psum slots
  int T  = B / 64;
  int nblk = T*(T+1)/2;            // triangular: by <= bx

  char* ws = (char*)d_ws;
  float*    psum     = (float*)(ws);                          // nprep*8 f32 (32KB)
  float*    pairPart = (float*)(ws + 65536);                  // nblk*4 f32 (~33KB)
  unsigned* rowMinU  = (unsigned*)(ws + 131072);              // B u32
  unsigned* rowMaxU  = (unsigned*)(ws + 131072 + (size_t)B*4);
  __bf16*   fb2      = (__bf16*)(ws + 131072 + (size_t)B*8);  // B*D bf16 tiled

  k_prep <<<nprep, 256, 0, stream>>>(features, fb2, logits, targets, alpha, fa, cw,
                                     B, D, psum, rowMinU, rowMaxU);
  k_pairs<<<nblk, 64, 0, stream>>>(fb2, targets, B, D, pairPart, rowMinU, rowMaxU);
  k_final<<<1, 1024, 0, stream>>>(targets, epoch, B, nprep, nblk, pairPart, psum,
                                  rowMinU, rowMaxU, (float*)d_out);
}